// Round 1
// baseline (655.509 us; speedup 1.0000x reference)
//
#include <hip/hip_runtime.h>
#include <math.h>

#define BQ 16384      // batch
#define KF 784        // quanv feature dim = 196*4
#define NH 256        // hidden dim
#define NCLS 10

// ======================= quanv (4-qubit statevector) =======================
// State: 16 complex amplitudes, index bit layout (w0,w1,w2,w3) = (8,4,2,1).
// Wire w <-> stride ST = 8 >> w.

template<int ST>
__device__ __forceinline__ void ry_gate(float* sr, float* si, float c, float s) {
#pragma unroll
  for (int i = 0; i < 16; i++) {
    if (i & ST) continue;
    const int j = i | ST;
    const float a0r = sr[i], a0i = si[i], a1r = sr[j], a1i = si[j];
    sr[i] = c * a0r - s * a1r;  si[i] = c * a0i - s * a1i;
    sr[j] = s * a0r + c * a1r;  si[j] = s * a0i + c * a1i;
  }
}

template<int ST>
__device__ __forceinline__ void rz_gate(float* sr, float* si, float c, float s) {
#pragma unroll
  for (int i = 0; i < 16; i++) {
    // bit=0: phase (c - i s); bit=1: phase (c + i s)
    const float pi_ = (i & ST) ? s : -s;
    const float ar = sr[i], ai = si[i];
    sr[i] = c * ar - pi_ * ai;
    si[i] = c * ai + pi_ * ar;
  }
}

template<int SC, int STG>
__device__ __forceinline__ void cnot_gate(float* sr, float* si) {
#pragma unroll
  for (int i = 0; i < 16; i++) {
    if (!(i & SC) || (i & STG)) continue;   // ctrl bit must be 1, tgt bit 0
    const int j = i | STG;
    float t;
    t = sr[i]; sr[i] = sr[j]; sr[j] = t;
    t = si[i]; si[i] = si[j]; si[j] = t;
  }
}

__global__ __launch_bounds__(64) void quanv_kernel(
    const float* __restrict__ x, const float* __restrict__ qp,
    float* __restrict__ feats) {
  const int b = blockIdx.x * 64 + threadIdx.x;
  const float* xb = x + (size_t)b * 784;
  float* fb = feats + (size_t)b * 784;

  float sr[16], si[16];
#pragma unroll
  for (int i = 0; i < 16; i++) { sr[i] = 0.f; si[i] = 0.f; }
  sr[0] = 1.f;

  // fixed-gate constants: index g = l*4 + wire
  float ryc[8], rys[8], rzc[8], rzs[8];
#pragma unroll
  for (int g = 0; g < 8; g++) {
    const float ta = qp[g * 2 + 0] * 0.5f;
    ryc[g] = cosf(ta); rys[g] = sinf(ta);
    const float tb = qp[g * 2 + 1] * 0.5f;
    rzc[g] = cosf(tb); rzs[g] = sinf(tb);
  }

  for (int r = 0; r < 14; r++) {
    const float* row0 = xb + (2 * r) * 28;
    const float* row1 = row0 + 28;
    for (int c = 0; c < 14; c++) {
      const float2 t0 = *(const float2*)(row0 + 2 * c);
      const float2 t1 = *(const float2*)(row1 + 2 * c);

      // encode: RY(vals[w]) on wire w, half-angle = v*0.5
      float h, cc, ss;
      h = t0.x * 0.5f; cc = __cosf(h); ss = __sinf(h); ry_gate<8>(sr, si, cc, ss);
      h = t0.y * 0.5f; cc = __cosf(h); ss = __sinf(h); ry_gate<4>(sr, si, cc, ss);
      h = t1.x * 0.5f; cc = __cosf(h); ss = __sinf(h); ry_gate<2>(sr, si, cc, ss);
      h = t1.y * 0.5f; cc = __cosf(h); ss = __sinf(h); ry_gate<1>(sr, si, cc, ss);

#pragma unroll
      for (int l = 0; l < 2; l++) {
        ry_gate<8>(sr, si, ryc[l * 4 + 0], rys[l * 4 + 0]);
        rz_gate<8>(sr, si, rzc[l * 4 + 0], rzs[l * 4 + 0]);
        ry_gate<4>(sr, si, ryc[l * 4 + 1], rys[l * 4 + 1]);
        rz_gate<4>(sr, si, rzc[l * 4 + 1], rzs[l * 4 + 1]);
        ry_gate<2>(sr, si, ryc[l * 4 + 2], rys[l * 4 + 2]);
        rz_gate<2>(sr, si, rzc[l * 4 + 2], rzs[l * 4 + 2]);
        ry_gate<1>(sr, si, ryc[l * 4 + 3], rys[l * 4 + 3]);
        rz_gate<1>(sr, si, rzc[l * 4 + 3], rzs[l * 4 + 3]);
        cnot_gate<8, 4>(sr, si);
        cnot_gate<4, 2>(sr, si);
        cnot_gate<2, 1>(sr, si);
      }

      // measure <Z_w>
      float p[16];
#pragma unroll
      for (int i = 0; i < 16; i++) p[i] = sr[i] * sr[i] + si[i] * si[i];
      float e0 = 0.f, e1 = 0.f, e2 = 0.f, e3 = 0.f;
#pragma unroll
      for (int i = 0; i < 16; i++) {
        e0 += (i & 8) ? -p[i] : p[i];
        e1 += (i & 4) ? -p[i] : p[i];
        e2 += (i & 2) ? -p[i] : p[i];
        e3 += (i & 1) ? -p[i] : p[i];
      }
      *(float4*)(fb + (r * 14 + c) * 4) = make_float4(e0, e1, e2, e3);
    }
  }
}

// ======================= fp32 NT GEMM: C = A(MxK) * B(NxK)^T + bias ========
#define BM 128
#define BN 64
#define BKK 16
#define PADA (BM + 4)   // 132 floats -> 528B rows, 16B-aligned
#define PADB (BN + 4)   // 68  floats -> 272B rows, 16B-aligned

__global__ __launch_bounds__(256) void gemm_nt_bias(
    const float* __restrict__ A, const float* __restrict__ B,
    const float* __restrict__ bias, float* __restrict__ C,
    int M, int N, int K) {
  __shared__ float As[BKK][PADA];
  __shared__ float Bs[BKK][PADB];
  const int tid = threadIdx.x;
  const int bm = blockIdx.x * BM;
  const int bn = blockIdx.y * BN;
  const int tx = tid & 15;   // N dir: 16 * 4 = 64
  const int ty = tid >> 4;   // M dir: 16 * 8 = 128

  float acc[8][4];
#pragma unroll
  for (int i = 0; i < 8; i++)
#pragma unroll
    for (int j = 0; j < 4; j++) acc[i][j] = 0.f;

  for (int k0 = 0; k0 < K; k0 += BKK) {
#pragma unroll
    for (int it = 0; it < 2; it++) {
      const int idx = tid + it * 256;          // 0..511
      const int m = idx >> 2;
      const int kq = (idx & 3) * 4;
      const float4 v = *(const float4*)(A + (size_t)(bm + m) * K + k0 + kq);
      As[kq + 0][m] = v.x; As[kq + 1][m] = v.y; As[kq + 2][m] = v.z; As[kq + 3][m] = v.w;
    }
    {
      const int n = tid >> 2;
      const int kq = (tid & 3) * 4;
      const float4 v = *(const float4*)(B + (size_t)(bn + n) * K + k0 + kq);
      Bs[kq + 0][n] = v.x; Bs[kq + 1][n] = v.y; Bs[kq + 2][n] = v.z; Bs[kq + 3][n] = v.w;
    }
    __syncthreads();
#pragma unroll
    for (int k = 0; k < BKK; k++) {
      const float4 va0 = *(const float4*)&As[k][ty * 8];
      const float4 va1 = *(const float4*)&As[k][ty * 8 + 4];
      const float4 vb  = *(const float4*)&Bs[k][tx * 4];
      const float a[8] = {va0.x, va0.y, va0.z, va0.w, va1.x, va1.y, va1.z, va1.w};
      const float bb[4] = {vb.x, vb.y, vb.z, vb.w};
#pragma unroll
      for (int i = 0; i < 8; i++)
#pragma unroll
        for (int j = 0; j < 4; j++) acc[i][j] += a[i] * bb[j];
    }
    __syncthreads();
  }

  const float4 bv = *(const float4*)(bias + bn + tx * 4);
#pragma unroll
  for (int i = 0; i < 8; i++) {
    const int row = bm + ty * 8 + i;
    float4 o;
    o.x = acc[i][0] + bv.x; o.y = acc[i][1] + bv.y;
    o.z = acc[i][2] + bv.z; o.w = acc[i][3] + bv.w;
    *(float4*)(C + (size_t)row * N + bn + tx * 4) = o;
  }
}

// ======================= BatchNorm (training stats) ========================
__global__ __launch_bounds__(256) void bn_partial(const float* __restrict__ h,
                                                  float* __restrict__ partial) {
  const int blk = blockIdx.x;      // 256 blocks x 64 rows
  const int t = threadIdx.x;       // column
  const float* p = h + (size_t)blk * 64 * NH + t;
  float s = 0.f, ss = 0.f;
#pragma unroll 4
  for (int r = 0; r < 64; r++) {
    const float v = p[(size_t)r * NH];
    s += v; ss += v * v;
  }
  partial[blk * 512 + t] = s;
  partial[blk * 512 + 256 + t] = ss;
}

__global__ __launch_bounds__(256) void bn_finalize(
    const float* __restrict__ partial, const float* __restrict__ g,
    const float* __restrict__ be, float* __restrict__ ab, float* __restrict__ cb) {
  const int t = threadIdx.x;
  float s = 0.f, ss = 0.f;
  for (int i = 0; i < 256; i++) {
    s += partial[i * 512 + t];
    ss += partial[i * 512 + 256 + t];
  }
  const float mean = s * (1.f / 16384.f);
  const float var = ss * (1.f / 16384.f) - mean * mean;
  const float rstd = rsqrtf(var + 1e-5f);
  const float a = g[t] * rstd;
  ab[t] = a;
  cb[t] = be[t] - mean * a;
}

__global__ __launch_bounds__(256) void bn_relu(float* __restrict__ h,
                                               const float* __restrict__ ab,
                                               const float* __restrict__ cb) {
  const size_t i = (size_t)blockIdx.x * 256 + threadIdx.x;  // float4 index
  float4 v = ((float4*)h)[i];
  const int col = (int)((i * 4) & (NH - 1));
  const float4 a = *(const float4*)(ab + col);
  const float4 c = *(const float4*)(cb + col);
  v.x = fmaxf(v.x * a.x + c.x, 0.f);
  v.y = fmaxf(v.y * a.y + c.y, 0.f);
  v.z = fmaxf(v.z * a.z + c.z, 0.f);
  v.w = fmaxf(v.w * a.w + c.w, 0.f);
  ((float4*)h)[i] = v;
}

__global__ __launch_bounds__(256) void bn_relu_res(float* __restrict__ h2,
                                                   const float* __restrict__ h1,
                                                   const float* __restrict__ ab,
                                                   const float* __restrict__ cb) {
  const size_t i = (size_t)blockIdx.x * 256 + threadIdx.x;
  float4 v = ((float4*)h2)[i];
  const float4 rsd = ((const float4*)h1)[i];
  const int col = (int)((i * 4) & (NH - 1));
  const float4 a = *(const float4*)(ab + col);
  const float4 c = *(const float4*)(cb + col);
  v.x = fmaxf(v.x * a.x + c.x, 0.f) + rsd.x;
  v.y = fmaxf(v.y * a.y + c.y, 0.f) + rsd.y;
  v.z = fmaxf(v.z * a.z + c.z, 0.f) + rsd.z;
  v.w = fmaxf(v.w * a.w + c.w, 0.f) + rsd.w;
  ((float4*)h2)[i] = v;
}

// ================ head: logits = h2 @ w3^T + b3, then log_softmax ==========
__global__ __launch_bounds__(256) void head_kernel(
    const float* __restrict__ h2, const float* __restrict__ w3,
    const float* __restrict__ b3, float* __restrict__ out) {
  __shared__ float w3s[NCLS * NH];
  for (int i = threadIdx.x; i < NCLS * NH; i += 256) w3s[i] = w3[i];
  __syncthreads();

  const int m = blockIdx.x * 256 + threadIdx.x;
  const float* hr = h2 + (size_t)m * NH;
  float acc[NCLS];
#pragma unroll
  for (int n = 0; n < NCLS; n++) acc[n] = b3[n];

  for (int k = 0; k < NH; k += 4) {
    const float4 hv = *(const float4*)(hr + k);
#pragma unroll
    for (int n = 0; n < NCLS; n++) {
      const float4 wv = *(const float4*)&w3s[n * NH + k];
      acc[n] += hv.x * wv.x + hv.y * wv.y + hv.z * wv.z + hv.w * wv.w;
    }
  }

  float mx = acc[0];
#pragma unroll
  for (int n = 1; n < NCLS; n++) mx = fmaxf(mx, acc[n]);
  float se = 0.f;
#pragma unroll
  for (int n = 0; n < NCLS; n++) se += expf(acc[n] - mx);
  const float lse = logf(se) + mx;
#pragma unroll
  for (int n = 0; n < NCLS; n++) out[(size_t)m * NCLS + n] = acc[n] - lse;
}

// =========================== launch ========================================
extern "C" void kernel_launch(void* const* d_in, const int* in_sizes, int n_in,
                              void* d_out, int out_size, void* d_ws, size_t ws_size,
                              hipStream_t stream) {
  const float* x   = (const float*)d_in[0];
  const float* qp  = (const float*)d_in[1];
  const float* w1  = (const float*)d_in[2];
  const float* b1  = (const float*)d_in[3];
  const float* g1  = (const float*)d_in[4];
  const float* be1 = (const float*)d_in[5];
  const float* w2  = (const float*)d_in[6];
  const float* b2  = (const float*)d_in[7];
  const float* g2  = (const float*)d_in[8];
  const float* be2 = (const float*)d_in[9];
  const float* w3  = (const float*)d_in[10];
  const float* b3  = (const float*)d_in[11];
  float* out = (float*)d_out;

  // workspace layout (floats); total ~85.5 MB
  float* ws      = (float*)d_ws;
  float* feats   = ws;                               // BQ*KF   = 12845056
  float* h1      = feats + (size_t)BQ * KF;          // BQ*NH   =  4194304
  float* h2      = h1 + (size_t)BQ * NH;             // BQ*NH
  float* partial = h2 + (size_t)BQ * NH;             // 256*512 =   131072
  float* ab1     = partial + 131072;
  float* cb1     = ab1 + 256;
  float* ab2     = cb1 + 256;
  float* cb2     = ab2 + 256;

  quanv_kernel<<<BQ / 64, 64, 0, stream>>>(x, qp, feats);

  gemm_nt_bias<<<dim3(BQ / BM, NH / BN), 256, 0, stream>>>(feats, w1, b1, h1, BQ, NH, KF);
  bn_partial<<<256, 256, 0, stream>>>(h1, partial);
  bn_finalize<<<1, 256, 0, stream>>>(partial, g1, be1, ab1, cb1);
  bn_relu<<<(BQ * NH / 4) / 256, 256, 0, stream>>>(h1, ab1, cb1);

  gemm_nt_bias<<<dim3(BQ / BM, NH / BN), 256, 0, stream>>>(h1, w2, b2, h2, BQ, NH, NH);
  bn_partial<<<256, 256, 0, stream>>>(h2, partial);
  bn_finalize<<<1, 256, 0, stream>>>(partial, g2, be2, ab2, cb2);
  bn_relu_res<<<(BQ * NH / 4) / 256, 256, 0, stream>>>(h2, h1, ab2, cb2);

  head_kernel<<<BQ / 256, 256, 0, stream>>>(h2, w3, b3, out);
}

// Round 2
// 406.203 us; speedup vs baseline: 1.6137x; 1.6137x over previous
//
#include <hip/hip_runtime.h>
#include <math.h>

#define BQ 16384      // batch
#define KF 784        // quanv feature dim = 196*4
#define NH 256        // hidden dim
#define NCLS 10

// ======================= quanv (4-qubit statevector) =======================
// State distributed over 4 lanes per batch element:
//   amp index i = (b3 b2 b1 b0), wires (0,1,2,3) <-> bits (3,2,1,0)
//   lane sub-id q = (b3<<1)|b2   (quad-aligned: lanes 4e..4e+3 = element e)
//   register r   = (b1<<1)|b0   (2 complex amps -> sr[4]/si[4] per lane... r in 0..3)
// Cross-lane wires 0,1 use DPP quad_perm (full-rate VALU, no LDS pipe).

#define XOR1 0xB1   // quad_perm [1,0,3,2]
#define XOR2 0x4E   // quad_perm [2,3,0,1]

template<int CTRL>
__device__ __forceinline__ float fdpp(float x) {
  return __int_as_float(
      __builtin_amdgcn_mov_dpp(__float_as_int(x), CTRL, 0xF, 0xF, false));
}

// RY on wire2 (reg bit1): pairs (0,2),(1,3)
__device__ __forceinline__ void ry_w2(float (&sr)[4], float (&si)[4], float c, float s) {
#pragma unroll
  for (int r = 0; r < 2; r++) {
    const float a0r = sr[r], a1r = sr[r + 2], a0i = si[r], a1i = si[r + 2];
    sr[r]     = c * a0r - s * a1r;       si[r]     = c * a0i - s * a1i;
    sr[r + 2] = fmaf(s, a0r, c * a1r);   si[r + 2] = fmaf(s, a0i, c * a1i);
  }
}
// RY on wire3 (reg bit0): pairs (0,1),(2,3)
__device__ __forceinline__ void ry_w3(float (&sr)[4], float (&si)[4], float c, float s) {
#pragma unroll
  for (int r = 0; r < 4; r += 2) {
    const float a0r = sr[r], a1r = sr[r + 1], a0i = si[r], a1i = si[r + 1];
    sr[r]     = c * a0r - s * a1r;       si[r]     = c * a0i - s * a1i;
    sr[r + 1] = fmaf(s, a0r, c * a1r);   si[r + 1] = fmaf(s, a0i, c * a1i);
  }
}
// RY on a lane-bit wire: partner via DPP; ss = (lane-bit ? +s : -s)
template<int CTRL>
__device__ __forceinline__ void ry_cross(float (&sr)[4], float (&si)[4], float c, float ss) {
#pragma unroll
  for (int r = 0; r < 4; r++) {
    const float tr = fdpp<CTRL>(sr[r]);
    const float ti = fdpp<CTRL>(si[r]);
    sr[r] = fmaf(ss, tr, c * sr[r]);
    si[r] = fmaf(ss, ti, c * si[r]);
  }
}
// RZ on a lane-bit wire: phase sign lane-uniform; pz = (bit ? +s : -s)
__device__ __forceinline__ void rz_lane(float (&sr)[4], float (&si)[4], float c, float pz) {
#pragma unroll
  for (int r = 0; r < 4; r++) {
    const float ar = sr[r], ai = si[r];
    sr[r] = c * ar - pz * ai;
    si[r] = fmaf(c, ai, pz * ar);
  }
}
// RZ on wire2 (reg bit1): regs 0,1 -> -s ; regs 2,3 -> +s  (compile-time signs)
__device__ __forceinline__ void rz_w2(float (&sr)[4], float (&si)[4], float c, float s) {
#pragma unroll
  for (int r = 0; r < 4; r++) {
    const float pz = (r & 2) ? s : -s;
    const float ar = sr[r], ai = si[r];
    sr[r] = c * ar - pz * ai;
    si[r] = fmaf(c, ai, pz * ar);
  }
}
// RZ on wire3 (reg bit0)
__device__ __forceinline__ void rz_w3(float (&sr)[4], float (&si)[4], float c, float s) {
#pragma unroll
  for (int r = 0; r < 4; r++) {
    const float pz = (r & 1) ? s : -s;
    const float ar = sr[r], ai = si[r];
    sr[r] = c * ar - pz * ai;
    si[r] = fmaf(c, ai, pz * ar);
  }
}

__global__ __launch_bounds__(256) void quanv_kernel(
    const float* __restrict__ x, const float* __restrict__ qp,
    float* __restrict__ feats) {
  const int g = blockIdx.x * 256 + threadIdx.x;   // 65536 threads
  const int b = g >> 2;
  const int q = g & 3;
  const float* xb = x + (size_t)b * 784;
  float* fb = feats + (size_t)b * 784;

  const float sg0 = (q & 2) ? 1.f : -1.f;   // +s when wire0 amp-bit set
  const float sg1 = (q & 1) ? 1.f : -1.f;
  const bool cn01 = (q & 2) != 0;           // CNOT(0,1) control (lane bit1)
  const bool cn12 = (q & 1) != 0;           // CNOT(1,2) control (lane bit0)

  // fixed-gate constants, g = l*4 + wire (computed once per thread)
  float ryc[8], rys[8], rzc[8], rzs[8];
#pragma unroll
  for (int gg = 0; gg < 8; gg++) {
    const float ta = qp[gg * 2 + 0] * 0.5f;
    ryc[gg] = cosf(ta); rys[gg] = sinf(ta);
    const float tb = qp[gg * 2 + 1] * 0.5f;
    rzc[gg] = cosf(tb); rzs[gg] = sinf(tb);
  }

  float sr[4] = {(q == 0) ? 1.f : 0.f, 0.f, 0.f, 0.f};
  float si[4] = {0.f, 0.f, 0.f, 0.f};

  for (int rr = 0; rr < 14; rr++) {
    const float* row0 = xb + (2 * rr) * 28;
    const float* row1 = row0 + 28;
    for (int cc = 0; cc < 14; cc++) {
      const float2 t0 = *(const float2*)(row0 + 2 * cc);
      const float2 t1 = *(const float2*)(row1 + 2 * cc);

      // encode RY(vals[w]) on wire w
      float h, c_, s_;
      h = t0.x * 0.5f; c_ = __cosf(h); s_ = __sinf(h); ry_cross<XOR2>(sr, si, c_, sg0 * s_);
      h = t0.y * 0.5f; c_ = __cosf(h); s_ = __sinf(h); ry_cross<XOR1>(sr, si, c_, sg1 * s_);
      h = t1.x * 0.5f; c_ = __cosf(h); s_ = __sinf(h); ry_w2(sr, si, c_, s_);
      h = t1.y * 0.5f; c_ = __cosf(h); s_ = __sinf(h); ry_w3(sr, si, c_, s_);

#pragma unroll
      for (int l = 0; l < 2; l++) {
        const int g0 = l * 4;
        ry_cross<XOR2>(sr, si, ryc[g0], sg0 * rys[g0]);
        rz_lane(sr, si, rzc[g0], sg0 * rzs[g0]);
        ry_cross<XOR1>(sr, si, ryc[g0 + 1], sg1 * rys[g0 + 1]);
        rz_lane(sr, si, rzc[g0 + 1], sg1 * rzs[g0 + 1]);
        ry_w2(sr, si, ryc[g0 + 2], rys[g0 + 2]);
        rz_w2(sr, si, rzc[g0 + 2], rzs[g0 + 2]);
        ry_w3(sr, si, ryc[g0 + 3], rys[g0 + 3]);
        rz_w3(sr, si, rzc[g0 + 3], rzs[g0 + 3]);

        // CNOT(0,1): lanes q=2,3 exchange (dpp xor1 + cndmask)
#pragma unroll
        for (int r = 0; r < 4; r++) {
          const float tr = fdpp<XOR1>(sr[r]);
          const float ti = fdpp<XOR1>(si[r]);
          sr[r] = cn01 ? tr : sr[r];
          si[r] = cn01 ? ti : si[r];
        }
        // CNOT(1,2): if lane bit0: swap regs (0,2),(1,3)
        {
          float t;
          t = sr[0]; sr[0] = cn12 ? sr[2] : sr[0]; sr[2] = cn12 ? t : sr[2];
          t = si[0]; si[0] = cn12 ? si[2] : si[0]; si[2] = cn12 ? t : si[2];
          t = sr[1]; sr[1] = cn12 ? sr[3] : sr[1]; sr[3] = cn12 ? t : sr[3];
          t = si[1]; si[1] = cn12 ? si[3] : si[1]; si[3] = cn12 ? t : si[3];
        }
        // CNOT(2,3): swap regs 2,3 (free rename)
        {
          float t;
          t = sr[2]; sr[2] = sr[3]; sr[3] = t;
          t = si[2]; si[2] = si[3]; si[3] = t;
        }
      }

      // measure <Z_w>
      const float p0 = sr[0] * sr[0] + si[0] * si[0];
      const float p1 = sr[1] * sr[1] + si[1] * si[1];
      const float p2 = sr[2] * sr[2] + si[2] * si[2];
      const float p3 = sr[3] * sr[3] + si[3] * si[3];
      const float s01 = p0 + p1, s23 = p2 + p3;
      const float d01 = p0 - p1, d23 = p2 - p3;
      const float tot = s01 + s23;
      float e0 = -sg0 * tot;       // + when wire0 bit clear
      float e1 = -sg1 * tot;
      float e2 = s01 - s23;
      float e3 = d01 + d23;
      e0 += fdpp<XOR1>(e0); e0 += fdpp<XOR2>(e0);
      e1 += fdpp<XOR1>(e1); e1 += fdpp<XOR2>(e1);
      e2 += fdpp<XOR1>(e2); e2 += fdpp<XOR2>(e2);
      e3 += fdpp<XOR1>(e3); e3 += fdpp<XOR2>(e3);
      const float e = (q == 0) ? e0 : (q == 1) ? e1 : (q == 2) ? e2 : e3;
      fb[(rr * 14 + cc) * 4 + q] = e;
    }
  }
}

// ======================= fp32 NT GEMM: C = A(MxK) * B(NxK)^T + bias ========
#define BM 128
#define BN 64
#define BKK 16
#define PADA (BM + 4)   // 132 floats -> 528B rows, 16B-aligned
#define PADB (BN + 4)   // 68  floats -> 272B rows, 16B-aligned

__global__ __launch_bounds__(256) void gemm_nt_bias(
    const float* __restrict__ A, const float* __restrict__ B,
    const float* __restrict__ bias, float* __restrict__ C,
    int M, int N, int K) {
  __shared__ float As[BKK][PADA];
  __shared__ float Bs[BKK][PADB];
  const int tid = threadIdx.x;
  const int bm = blockIdx.x * BM;
  const int bn = blockIdx.y * BN;
  const int tx = tid & 15;   // N dir: 16 * 4 = 64
  const int ty = tid >> 4;   // M dir: 16 * 8 = 128

  float acc[8][4];
#pragma unroll
  for (int i = 0; i < 8; i++)
#pragma unroll
    for (int j = 0; j < 4; j++) acc[i][j] = 0.f;

  for (int k0 = 0; k0 < K; k0 += BKK) {
#pragma unroll
    for (int it = 0; it < 2; it++) {
      const int idx = tid + it * 256;          // 0..511
      const int m = idx >> 2;
      const int kq = (idx & 3) * 4;
      const float4 v = *(const float4*)(A + (size_t)(bm + m) * K + k0 + kq);
      As[kq + 0][m] = v.x; As[kq + 1][m] = v.y; As[kq + 2][m] = v.z; As[kq + 3][m] = v.w;
    }
    {
      const int n = tid >> 2;
      const int kq = (tid & 3) * 4;
      const float4 v = *(const float4*)(B + (size_t)(bn + n) * K + k0 + kq);
      Bs[kq + 0][n] = v.x; Bs[kq + 1][n] = v.y; Bs[kq + 2][n] = v.z; Bs[kq + 3][n] = v.w;
    }
    __syncthreads();
#pragma unroll
    for (int k = 0; k < BKK; k++) {
      const float4 va0 = *(const float4*)&As[k][ty * 8];
      const float4 va1 = *(const float4*)&As[k][ty * 8 + 4];
      const float4 vb  = *(const float4*)&Bs[k][tx * 4];
      const float a[8] = {va0.x, va0.y, va0.z, va0.w, va1.x, va1.y, va1.z, va1.w};
      const float bb[4] = {vb.x, vb.y, vb.z, vb.w};
#pragma unroll
      for (int i = 0; i < 8; i++)
#pragma unroll
        for (int j = 0; j < 4; j++) acc[i][j] += a[i] * bb[j];
    }
    __syncthreads();
  }

  const float4 bv = *(const float4*)(bias + bn + tx * 4);
#pragma unroll
  for (int i = 0; i < 8; i++) {
    const int row = bm + ty * 8 + i;
    float4 o;
    o.x = acc[i][0] + bv.x; o.y = acc[i][1] + bv.y;
    o.z = acc[i][2] + bv.z; o.w = acc[i][3] + bv.w;
    *(float4*)(C + (size_t)row * N + bn + tx * 4) = o;
  }
}

// ======================= BatchNorm (training stats) ========================
__global__ __launch_bounds__(256) void bn_partial(const float* __restrict__ h,
                                                  float* __restrict__ partial) {
  const int blk = blockIdx.x;      // 256 blocks x 64 rows
  const int t = threadIdx.x;       // column
  const float* p = h + (size_t)blk * 64 * NH + t;
  float s = 0.f, ss = 0.f;
#pragma unroll 4
  for (int r = 0; r < 64; r++) {
    const float v = p[(size_t)r * NH];
    s += v; ss += v * v;
  }
  partial[blk * 512 + t] = s;
  partial[blk * 512 + 256 + t] = ss;
}

__global__ __launch_bounds__(256) void bn_finalize(
    const float* __restrict__ partial, const float* __restrict__ g,
    const float* __restrict__ be, float* __restrict__ ab, float* __restrict__ cb) {
  const int t = threadIdx.x;
  float s = 0.f, ss = 0.f;
  for (int i = 0; i < 256; i++) {
    s += partial[i * 512 + t];
    ss += partial[i * 512 + 256 + t];
  }
  const float mean = s * (1.f / 16384.f);
  const float var = ss * (1.f / 16384.f) - mean * mean;
  const float rstd = rsqrtf(var + 1e-5f);
  const float a = g[t] * rstd;
  ab[t] = a;
  cb[t] = be[t] - mean * a;
}

__global__ __launch_bounds__(256) void bn_relu(float* __restrict__ h,
                                               const float* __restrict__ ab,
                                               const float* __restrict__ cb) {
  const size_t i = (size_t)blockIdx.x * 256 + threadIdx.x;  // float4 index
  float4 v = ((float4*)h)[i];
  const int col = (int)((i * 4) & (NH - 1));
  const float4 a = *(const float4*)(ab + col);
  const float4 c = *(const float4*)(cb + col);
  v.x = fmaxf(v.x * a.x + c.x, 0.f);
  v.y = fmaxf(v.y * a.y + c.y, 0.f);
  v.z = fmaxf(v.z * a.z + c.z, 0.f);
  v.w = fmaxf(v.w * a.w + c.w, 0.f);
  ((float4*)h)[i] = v;
}

__global__ __launch_bounds__(256) void bn_relu_res(float* __restrict__ h2,
                                                   const float* __restrict__ h1,
                                                   const float* __restrict__ ab,
                                                   const float* __restrict__ cb) {
  const size_t i = (size_t)blockIdx.x * 256 + threadIdx.x;
  float4 v = ((float4*)h2)[i];
  const float4 rsd = ((const float4*)h1)[i];
  const int col = (int)((i * 4) & (NH - 1));
  const float4 a = *(const float4*)(ab + col);
  const float4 c = *(const float4*)(cb + col);
  v.x = fmaxf(v.x * a.x + c.x, 0.f) + rsd.x;
  v.y = fmaxf(v.y * a.y + c.y, 0.f) + rsd.y;
  v.z = fmaxf(v.z * a.z + c.z, 0.f) + rsd.z;
  v.w = fmaxf(v.w * a.w + c.w, 0.f) + rsd.w;
  ((float4*)h2)[i] = v;
}

// ================ head: logits = h2 @ w3^T + b3, then log_softmax ==========
__global__ __launch_bounds__(256) void head_kernel(
    const float* __restrict__ h2, const float* __restrict__ w3,
    const float* __restrict__ b3, float* __restrict__ out) {
  __shared__ float w3s[NCLS * NH];
  for (int i = threadIdx.x; i < NCLS * NH; i += 256) w3s[i] = w3[i];
  __syncthreads();

  const int m = blockIdx.x * 256 + threadIdx.x;
  const float* hr = h2 + (size_t)m * NH;
  float acc[NCLS];
#pragma unroll
  for (int n = 0; n < NCLS; n++) acc[n] = b3[n];

  for (int k = 0; k < NH; k += 4) {
    const float4 hv = *(const float4*)(hr + k);
#pragma unroll
    for (int n = 0; n < NCLS; n++) {
      const float4 wv = *(const float4*)&w3s[n * NH + k];
      acc[n] += hv.x * wv.x + hv.y * wv.y + hv.z * wv.z + hv.w * wv.w;
    }
  }

  float mx = acc[0];
#pragma unroll
  for (int n = 1; n < NCLS; n++) mx = fmaxf(mx, acc[n]);
  float se = 0.f;
#pragma unroll
  for (int n = 0; n < NCLS; n++) se += expf(acc[n] - mx);
  const float lse = logf(se) + mx;
#pragma unroll
  for (int n = 0; n < NCLS; n++) out[(size_t)m * NCLS + n] = acc[n] - lse;
}

// =========================== launch ========================================
extern "C" void kernel_launch(void* const* d_in, const int* in_sizes, int n_in,
                              void* d_out, int out_size, void* d_ws, size_t ws_size,
                              hipStream_t stream) {
  const float* x   = (const float*)d_in[0];
  const float* qp  = (const float*)d_in[1];
  const float* w1  = (const float*)d_in[2];
  const float* b1  = (const float*)d_in[3];
  const float* g1  = (const float*)d_in[4];
  const float* be1 = (const float*)d_in[5];
  const float* w2  = (const float*)d_in[6];
  const float* b2  = (const float*)d_in[7];
  const float* g2  = (const float*)d_in[8];
  const float* be2 = (const float*)d_in[9];
  const float* w3  = (const float*)d_in[10];
  const float* b3  = (const float*)d_in[11];
  float* out = (float*)d_out;

  float* ws      = (float*)d_ws;
  float* feats   = ws;                               // BQ*KF
  float* h1      = feats + (size_t)BQ * KF;          // BQ*NH
  float* h2      = h1 + (size_t)BQ * NH;             // BQ*NH
  float* partial = h2 + (size_t)BQ * NH;             // 256*512
  float* ab1     = partial + 131072;
  float* cb1     = ab1 + 256;
  float* ab2     = cb1 + 256;
  float* cb2     = ab2 + 256;

  quanv_kernel<<<(BQ * 4) / 256, 256, 0, stream>>>(x, qp, feats);

  gemm_nt_bias<<<dim3(BQ / BM, NH / BN), 256, 0, stream>>>(feats, w1, b1, h1, BQ, NH, KF);
  bn_partial<<<256, 256, 0, stream>>>(h1, partial);
  bn_finalize<<<1, 256, 0, stream>>>(partial, g1, be1, ab1, cb1);
  bn_relu<<<(BQ * NH / 4) / 256, 256, 0, stream>>>(h1, ab1, cb1);

  gemm_nt_bias<<<dim3(BQ / BM, NH / BN), 256, 0, stream>>>(h1, w2, b2, h2, BQ, NH, NH);
  bn_partial<<<256, 256, 0, stream>>>(h2, partial);
  bn_finalize<<<1, 256, 0, stream>>>(partial, g2, be2, ab2, cb2);
  bn_relu_res<<<(BQ * NH / 4) / 256, 256, 0, stream>>>(h2, h1, ab2, cb2);

  head_kernel<<<BQ / 256, 256, 0, stream>>>(h2, w3, b3, out);
}

// Round 3
// 401.206 us; speedup vs baseline: 1.6338x; 1.0125x over previous
//
#include <hip/hip_runtime.h>
#include <math.h>

#define BQ 16384      // batch
#define KF 784        // quanv feature dim = 196*4
#define NH 256        // hidden dim
#define NCLS 10

// ======================= quanv (4-qubit statevector) =======================
// State distributed over 8 lanes per batch element, 2 complex amps per lane.
// Amp index bits: wire0 -> lane bit3 (xor8 = DPP row_ror:8)
//                 wire1 -> lane bit1 (xor2 = quad_perm 0x4E)
//                 wire2 -> lane bit0 (xor1 = quad_perm 0xB1)
//                 wire3 -> register index r in {0,1}
// Element id within wave = lane bits {2,4,5}. All comms are full-rate DPP.

#define XOR1 0xB1    // quad_perm [1,0,3,2]
#define XOR2 0x4E    // quad_perm [2,3,0,1]
#define ROR8 0x128   // row_ror:8 == xor8 within 16-lane row

template<int CTRL>
__device__ __forceinline__ float fdpp(float x) {
  return __int_as_float(
      __builtin_amdgcn_mov_dpp(__float_as_int(x), CTRL, 0xF, 0xF, false));
}

// RY on a lane-bit wire: partner via DPP; ss = (lane amp-bit ? +s : -s)
template<int CTRL>
__device__ __forceinline__ void ry_comm(float (&sr)[2], float (&si)[2],
                                        float c, float ss) {
  const float tr0 = fdpp<CTRL>(sr[0]);
  const float ti0 = fdpp<CTRL>(si[0]);
  const float tr1 = fdpp<CTRL>(sr[1]);
  const float ti1 = fdpp<CTRL>(si[1]);
  sr[0] = fmaf(ss, tr0, c * sr[0]);
  si[0] = fmaf(ss, ti0, c * si[0]);
  sr[1] = fmaf(ss, tr1, c * sr[1]);
  si[1] = fmaf(ss, ti1, c * si[1]);
}

// RY on wire3 (register bit): pair (reg0, reg1)
__device__ __forceinline__ void ry_reg(float (&sr)[2], float (&si)[2],
                                       float c, float s) {
  const float a0r = sr[0], a0i = si[0], a1r = sr[1], a1i = si[1];
  sr[0] = fmaf(-s, a1r, c * a0r);
  si[0] = fmaf(-s, a1i, c * a0i);
  sr[1] = fmaf(s, a0r, c * a1r);
  si[1] = fmaf(s, a0i, c * a1i);
}

// RZ on a lane-bit wire: pz = (bit ? +s : -s), lane-uniform
__device__ __forceinline__ void rz_lane(float (&sr)[2], float (&si)[2],
                                        float c, float pz) {
#pragma unroll
  for (int r = 0; r < 2; r++) {
    const float ar = sr[r], ai = si[r];
    sr[r] = fmaf(-pz, ai, c * ar);
    si[r] = fmaf(pz, ar, c * ai);
  }
}

// RZ on wire3 (register bit): reg0 pz=-s, reg1 pz=+s
__device__ __forceinline__ void rz_reg3(float (&sr)[2], float (&si)[2],
                                        float c, float s) {
  const float a0r = sr[0], a0i = si[0], a1r = sr[1], a1i = si[1];
  sr[0] = fmaf(s, a0i, c * a0r);
  si[0] = fmaf(-s, a0r, c * a0i);
  sr[1] = fmaf(-s, a1i, c * a1r);
  si[1] = fmaf(s, a1r, c * a1i);
}

// CNOT with lane-bit target: exchange along CTRL where sel (ctrl bit) is set
template<int CTRL>
__device__ __forceinline__ void cnot_comm(float (&sr)[2], float (&si)[2],
                                          bool sel) {
  const float tr0 = fdpp<CTRL>(sr[0]);
  const float ti0 = fdpp<CTRL>(si[0]);
  const float tr1 = fdpp<CTRL>(sr[1]);
  const float ti1 = fdpp<CTRL>(si[1]);
  sr[0] = sel ? tr0 : sr[0];
  si[0] = sel ? ti0 : si[0];
  sr[1] = sel ? tr1 : sr[1];
  si[1] = sel ? ti1 : si[1];
}

// CNOT(2,3): swap reg0<->reg1 where wire2 lane-bit set
__device__ __forceinline__ void cnot23(float (&sr)[2], float (&si)[2],
                                       bool sel) {
  const float tr = sr[0], ti = si[0];
  sr[0] = sel ? sr[1] : sr[0];
  si[0] = sel ? si[1] : si[0];
  sr[1] = sel ? tr : sr[1];
  si[1] = sel ? ti : si[1];
}

__global__ __launch_bounds__(256) void quanv_kernel(
    const float* __restrict__ x, const float* __restrict__ qp,
    float* __restrict__ feats) {
  const int tid = threadIdx.x;
  const int l = tid & 63;
  const int wv = tid >> 6;
  // sub-lane pattern over bits (b3,b1,b0)
  const int sub = ((l >> 3) & 1) * 4 + ((l >> 1) & 1) * 2 + (l & 1);
  const int e = ((l >> 4) << 1) | ((l >> 2) & 1);        // element in wave
  const int b = blockIdx.x * 32 + wv * 8 + e;

  const float sg0 = ((l >> 3) & 1) ? 1.f : -1.f;   // wire0 amp-bit sign
  const float sg1 = ((l >> 1) & 1) ? 1.f : -1.f;   // wire1
  const float sg2 = (l & 1) ? 1.f : -1.f;          // wire2
  const bool cn01 = ((l >> 3) & 1) != 0;           // ctrl wire0
  const bool cn12 = ((l >> 1) & 1) != 0;           // ctrl wire1
  const bool cn23 = (l & 1) != 0;                  // ctrl wire2
  const bool wen = (sub == 0) || (sub == 1) || (sub == 2) || (sub == 4);
  const int col = (sub == 4) ? 0 : (sub == 2) ? 1 : (sub == 1) ? 2 : 3;
  const bool use_e3 = (sub == 0);

  const float* xb = x + (size_t)b * 784;
  float* fb = feats + (size_t)b * 784;

  // fixed-gate constants, g = l*4 + wire; fold lane sign into s for wires 0-2
  float ryc[8], rysf[8], rzc[8], rzsf[8];
#pragma unroll
  for (int g = 0; g < 8; g++) {
    const int w = g & 3;
    const float sgw = (w == 0) ? sg0 : (w == 1) ? sg1 : (w == 2) ? sg2 : 1.f;
    const float ta = qp[g * 2 + 0] * 0.5f;
    ryc[g] = cosf(ta); rysf[g] = sgw * sinf(ta);
    const float tb = qp[g * 2 + 1] * 0.5f;
    rzc[g] = cosf(tb); rzsf[g] = sgw * sinf(tb);
  }

  float sr[2] = {(sub == 0) ? 1.f : 0.f, 0.f};
  float si[2] = {0.f, 0.f};

  float2 t0 = *(const float2*)(xb);
  float2 t1 = *(const float2*)(xb + 28);
  int nrr = 0, ncc = 0;

  for (int it = 0; it < 196; ++it) {
    // ---- prefetch next patch (hides VMEM latency under the gate block) ----
    int nc = ncc + 1, nr = nrr;
    if (nc == 14) { nc = 0; nr = nrr + 1; }
    const float* np = (it < 195) ? (xb + (2 * nr) * 28 + 2 * nc) : xb;
    const float2 n0 = *(const float2*)np;
    const float2 n1 = *(const float2*)(np + 28);

    // ---- encode: RY(v_w) on wire w ----
    float h, c_, s_;
    h = t0.x * 0.5f; c_ = __cosf(h); s_ = __sinf(h); ry_comm<ROR8>(sr, si, c_, sg0 * s_);
    h = t0.y * 0.5f; c_ = __cosf(h); s_ = __sinf(h); ry_comm<XOR2>(sr, si, c_, sg1 * s_);
    h = t1.x * 0.5f; c_ = __cosf(h); s_ = __sinf(h); ry_comm<XOR1>(sr, si, c_, sg2 * s_);
    h = t1.y * 0.5f; c_ = __cosf(h); s_ = __sinf(h); ry_reg(sr, si, c_, s_);

    // ---- 2 parameterized layers ----
#pragma unroll
    for (int ll = 0; ll < 2; ll++) {
      const int g0 = ll * 4;
      ry_comm<ROR8>(sr, si, ryc[g0 + 0], rysf[g0 + 0]);
      rz_lane(sr, si, rzc[g0 + 0], rzsf[g0 + 0]);
      ry_comm<XOR2>(sr, si, ryc[g0 + 1], rysf[g0 + 1]);
      rz_lane(sr, si, rzc[g0 + 1], rzsf[g0 + 1]);
      ry_comm<XOR1>(sr, si, ryc[g0 + 2], rysf[g0 + 2]);
      rz_lane(sr, si, rzc[g0 + 2], rzsf[g0 + 2]);
      ry_reg(sr, si, ryc[g0 + 3], rysf[g0 + 3]);
      rz_reg3(sr, si, rzc[g0 + 3], rzsf[g0 + 3]);
      cnot_comm<XOR2>(sr, si, cn01);   // CNOT(0,1): target wire1 = bit1
      cnot_comm<XOR1>(sr, si, cn12);   // CNOT(1,2): target wire2 = bit0
      cnot23(sr, si, cn23);            // CNOT(2,3): reg swap
    }

    // ---- measure <Z_w> via signed butterfly (WHT over lane bits) ----
    const float p0 = fmaf(sr[0], sr[0], si[0] * si[0]);
    const float p1 = fmaf(sr[1], sr[1], si[1] * si[1]);
    const float ps = p0 + p1;     // summed over wire3
    const float pd = p0 - p1;     // signed by wire3
    // WHT: stage sign = (bit ? -1 : +1) = -sg
    float v = ps;
    v = fmaf(-sg2, v, fdpp<XOR1>(v));
    v = fmaf(-sg1, v, fdpp<XOR2>(v));
    v = fmaf(-sg0, v, fdpp<ROR8>(v));
    // e3: plain sum of pd over all 8 sub-lanes
    float u = pd;
    u += fdpp<XOR1>(u);
    u += fdpp<XOR2>(u);
    u += fdpp<ROR8>(u);

    const float val = use_e3 ? u : v;
    if (wen) fb[it * 4 + col] = val;

    t0 = n0; t1 = n1; ncc = nc; nrr = nr;
  }
}

// ======================= fp32 NT GEMM: C = A(MxK) * B(NxK)^T + bias ========
#define BM 128
#define BN 64
#define BKK 16
#define PADA (BM + 4)   // 132 floats -> 528B rows, 16B-aligned
#define PADB (BN + 4)   // 68  floats -> 272B rows, 16B-aligned

__global__ __launch_bounds__(256) void gemm_nt_bias(
    const float* __restrict__ A, const float* __restrict__ B,
    const float* __restrict__ bias, float* __restrict__ C,
    int M, int N, int K) {
  __shared__ float As[BKK][PADA];
  __shared__ float Bs[BKK][PADB];
  const int tid = threadIdx.x;
  const int bm = blockIdx.x * BM;
  const int bn = blockIdx.y * BN;
  const int tx = tid & 15;   // N dir: 16 * 4 = 64
  const int ty = tid >> 4;   // M dir: 16 * 8 = 128

  float acc[8][4];
#pragma unroll
  for (int i = 0; i < 8; i++)
#pragma unroll
    for (int j = 0; j < 4; j++) acc[i][j] = 0.f;

  for (int k0 = 0; k0 < K; k0 += BKK) {
#pragma unroll
    for (int it = 0; it < 2; it++) {
      const int idx = tid + it * 256;          // 0..511
      const int m = idx >> 2;
      const int kq = (idx & 3) * 4;
      const float4 v = *(const float4*)(A + (size_t)(bm + m) * K + k0 + kq);
      As[kq + 0][m] = v.x; As[kq + 1][m] = v.y; As[kq + 2][m] = v.z; As[kq + 3][m] = v.w;
    }
    {
      const int n = tid >> 2;
      const int kq = (tid & 3) * 4;
      const float4 v = *(const float4*)(B + (size_t)(bn + n) * K + k0 + kq);
      Bs[kq + 0][n] = v.x; Bs[kq + 1][n] = v.y; Bs[kq + 2][n] = v.z; Bs[kq + 3][n] = v.w;
    }
    __syncthreads();
#pragma unroll
    for (int k = 0; k < BKK; k++) {
      const float4 va0 = *(const float4*)&As[k][ty * 8];
      const float4 va1 = *(const float4*)&As[k][ty * 8 + 4];
      const float4 vb  = *(const float4*)&Bs[k][tx * 4];
      const float a[8] = {va0.x, va0.y, va0.z, va0.w, va1.x, va1.y, va1.z, va1.w};
      const float bb[4] = {vb.x, vb.y, vb.z, vb.w};
#pragma unroll
      for (int i = 0; i < 8; i++)
#pragma unroll
        for (int j = 0; j < 4; j++) acc[i][j] += a[i] * bb[j];
    }
    __syncthreads();
  }

  const float4 bv = *(const float4*)(bias + bn + tx * 4);
#pragma unroll
  for (int i = 0; i < 8; i++) {
    const int row = bm + ty * 8 + i;
    float4 o;
    o.x = acc[i][0] + bv.x; o.y = acc[i][1] + bv.y;
    o.z = acc[i][2] + bv.z; o.w = acc[i][3] + bv.w;
    *(float4*)(C + (size_t)row * N + bn + tx * 4) = o;
  }
}

// ======================= BatchNorm (training stats) ========================
__global__ __launch_bounds__(256) void bn_partial(const float* __restrict__ h,
                                                  float* __restrict__ partial) {
  const int blk = blockIdx.x;      // 256 blocks x 64 rows
  const int t = threadIdx.x;       // column
  const float* p = h + (size_t)blk * 64 * NH + t;
  float s = 0.f, ss = 0.f;
#pragma unroll 4
  for (int r = 0; r < 64; r++) {
    const float v = p[(size_t)r * NH];
    s += v; ss += v * v;
  }
  partial[blk * 512 + t] = s;
  partial[blk * 512 + 256 + t] = ss;
}

__global__ __launch_bounds__(256) void bn_finalize(
    const float* __restrict__ partial, const float* __restrict__ g,
    const float* __restrict__ be, float* __restrict__ ab, float* __restrict__ cb) {
  const int t = threadIdx.x;
  float s = 0.f, ss = 0.f;
  for (int i = 0; i < 256; i++) {
    s += partial[i * 512 + t];
    ss += partial[i * 512 + 256 + t];
  }
  const float mean = s * (1.f / 16384.f);
  const float var = ss * (1.f / 16384.f) - mean * mean;
  const float rstd = rsqrtf(var + 1e-5f);
  const float a = g[t] * rstd;
  ab[t] = a;
  cb[t] = be[t] - mean * a;
}

__global__ __launch_bounds__(256) void bn_relu(float* __restrict__ h,
                                               const float* __restrict__ ab,
                                               const float* __restrict__ cb) {
  const size_t i = (size_t)blockIdx.x * 256 + threadIdx.x;  // float4 index
  float4 v = ((float4*)h)[i];
  const int col = (int)((i * 4) & (NH - 1));
  const float4 a = *(const float4*)(ab + col);
  const float4 c = *(const float4*)(cb + col);
  v.x = fmaxf(v.x * a.x + c.x, 0.f);
  v.y = fmaxf(v.y * a.y + c.y, 0.f);
  v.z = fmaxf(v.z * a.z + c.z, 0.f);
  v.w = fmaxf(v.w * a.w + c.w, 0.f);
  ((float4*)h)[i] = v;
}

__global__ __launch_bounds__(256) void bn_relu_res(float* __restrict__ h2,
                                                   const float* __restrict__ h1,
                                                   const float* __restrict__ ab,
                                                   const float* __restrict__ cb) {
  const size_t i = (size_t)blockIdx.x * 256 + threadIdx.x;
  float4 v = ((float4*)h2)[i];
  const float4 rsd = ((const float4*)h1)[i];
  const int col = (int)((i * 4) & (NH - 1));
  const float4 a = *(const float4*)(ab + col);
  const float4 c = *(const float4*)(cb + col);
  v.x = fmaxf(v.x * a.x + c.x, 0.f) + rsd.x;
  v.y = fmaxf(v.y * a.y + c.y, 0.f) + rsd.y;
  v.z = fmaxf(v.z * a.z + c.z, 0.f) + rsd.z;
  v.w = fmaxf(v.w * a.w + c.w, 0.f) + rsd.w;
  ((float4*)h2)[i] = v;
}

// ================ head: logits = h2 @ w3^T + b3, then log_softmax ==========
__global__ __launch_bounds__(256) void head_kernel(
    const float* __restrict__ h2, const float* __restrict__ w3,
    const float* __restrict__ b3, float* __restrict__ out) {
  __shared__ float w3s[NCLS * NH];
  for (int i = threadIdx.x; i < NCLS * NH; i += 256) w3s[i] = w3[i];
  __syncthreads();

  const int m = blockIdx.x * 256 + threadIdx.x;
  const float* hr = h2 + (size_t)m * NH;
  float acc[NCLS];
#pragma unroll
  for (int n = 0; n < NCLS; n++) acc[n] = b3[n];

  for (int k = 0; k < NH; k += 4) {
    const float4 hv = *(const float4*)(hr + k);
#pragma unroll
    for (int n = 0; n < NCLS; n++) {
      const float4 wv = *(const float4*)&w3s[n * NH + k];
      acc[n] += hv.x * wv.x + hv.y * wv.y + hv.z * wv.z + hv.w * wv.w;
    }
  }

  float mx = acc[0];
#pragma unroll
  for (int n = 1; n < NCLS; n++) mx = fmaxf(mx, acc[n]);
  float se = 0.f;
#pragma unroll
  for (int n = 0; n < NCLS; n++) se += expf(acc[n] - mx);
  const float lse = logf(se) + mx;
#pragma unroll
  for (int n = 0; n < NCLS; n++) out[(size_t)m * NCLS + n] = acc[n] - lse;
}

// =========================== launch ========================================
extern "C" void kernel_launch(void* const* d_in, const int* in_sizes, int n_in,
                              void* d_out, int out_size, void* d_ws, size_t ws_size,
                              hipStream_t stream) {
  const float* x   = (const float*)d_in[0];
  const float* qp  = (const float*)d_in[1];
  const float* w1  = (const float*)d_in[2];
  const float* b1  = (const float*)d_in[3];
  const float* g1  = (const float*)d_in[4];
  const float* be1 = (const float*)d_in[5];
  const float* w2  = (const float*)d_in[6];
  const float* b2  = (const float*)d_in[7];
  const float* g2  = (const float*)d_in[8];
  const float* be2 = (const float*)d_in[9];
  const float* w3  = (const float*)d_in[10];
  const float* b3  = (const float*)d_in[11];
  float* out = (float*)d_out;

  float* ws      = (float*)d_ws;
  float* feats   = ws;                               // BQ*KF
  float* h1      = feats + (size_t)BQ * KF;          // BQ*NH
  float* h2      = h1 + (size_t)BQ * NH;             // BQ*NH
  float* partial = h2 + (size_t)BQ * NH;             // 256*512
  float* ab1     = partial + 131072;
  float* cb1     = ab1 + 256;
  float* ab2     = cb1 + 256;
  float* cb2     = ab2 + 256;

  // 8 lanes/element: 16384*8 threads, 256/block -> 512 blocks (2 blocks/CU)
  quanv_kernel<<<(BQ * 8) / 256, 256, 0, stream>>>(x, qp, feats);

  gemm_nt_bias<<<dim3(BQ / BM, NH / BN), 256, 0, stream>>>(feats, w1, b1, h1, BQ, NH, KF);
  bn_partial<<<256, 256, 0, stream>>>(h1, partial);
  bn_finalize<<<1, 256, 0, stream>>>(partial, g1, be1, ab1, cb1);
  bn_relu<<<(BQ * NH / 4) / 256, 256, 0, stream>>>(h1, ab1, cb1);

  gemm_nt_bias<<<dim3(BQ / BM, NH / BN), 256, 0, stream>>>(h1, w2, b2, h2, BQ, NH, NH);
  bn_partial<<<256, 256, 0, stream>>>(h2, partial);
  bn_finalize<<<1, 256, 0, stream>>>(partial, g2, be2, ab2, cb2);
  bn_relu_res<<<(BQ * NH / 4) / 256, 256, 0, stream>>>(h2, h1, ab2, cb2);

  head_kernel<<<BQ / 256, 256, 0, stream>>>(h2, w3, b3, out);
}

// Round 4
// 293.973 us; speedup vs baseline: 2.2298x; 1.3648x over previous
//
#include <hip/hip_runtime.h>
#include <math.h>

#define BQ 16384      // batch
#define KFP 800       // padded quanv feature dim (196*4 = 784, +16 zero pad)
#define NH 256        // hidden dim
#define NCLS 10

typedef float f32x2 __attribute__((ext_vector_type(2)));
typedef float f32x4 __attribute__((ext_vector_type(4)));
typedef __bf16 bf16x8 __attribute__((ext_vector_type(8)));
typedef __bf16 bf16x4 __attribute__((ext_vector_type(4)));

// ======================= quanv (4-qubit statevector) =======================
// 8 lanes/element, 2 complex amps/lane, packed-fp32 (v_pk_*) arithmetic.
// wire0 -> lane bit3 (ROR8), wire1 -> lane bit1 (XOR2), wire2 -> lane bit0
// (XOR1), wire3 -> register half (f32x2 lo/hi). All comms full-rate DPP.

#define XOR1 0xB1    // quad_perm [1,0,3,2]
#define XOR2 0x4E    // quad_perm [2,3,0,1]
#define ROR8 0x128   // row_ror:8 == xor8 within 16-lane row

template<int CTRL>
__device__ __forceinline__ float fdpp(float x) {
  return __int_as_float(
      __builtin_amdgcn_mov_dpp(__float_as_int(x), CTRL, 0xF, 0xF, false));
}
template<int CTRL>
__device__ __forceinline__ f32x2 dpp2(f32x2 x) {
  f32x2 r; r.x = fdpp<CTRL>(x.x); r.y = fdpp<CTRL>(x.y); return r;
}
__device__ __forceinline__ f32x2 vfma(f32x2 a, f32x2 b, f32x2 c) {
  return __builtin_elementwise_fma(a, b, c);
}
__device__ __forceinline__ f32x2 splat(float v) { f32x2 r; r.x = v; r.y = v; return r; }
__device__ __forceinline__ f32x2 mk2(float a, float b) { f32x2 r; r.x = a; r.y = b; return r; }
__device__ __forceinline__ f32x2 vswap(f32x2 v) { return __builtin_shufflevector(v, v, 1, 0); }

// RY on a lane-bit wire: R = c*R + sv*dpp(R)   (sv carries the lane sign)
template<int CTRL>
__device__ __forceinline__ void ry_comm(f32x2& R, f32x2& I, f32x2 cc, f32x2 sv) {
  R = vfma(sv, dpp2<CTRL>(R), cc * R);
  I = vfma(sv, dpp2<CTRL>(I), cc * I);
}
// RY on wire3 (register halves): sv = (-s, +s)
__device__ __forceinline__ void ry_reg(f32x2& R, f32x2& I, f32x2 cc, f32x2 sv) {
  R = vfma(sv, vswap(R), cc * R);
  I = vfma(sv, vswap(I), cc * I);
}
// RZ any wire: per-half phase pzv; R' = c*R - pzv*I ; I' = c*I + pzv*R
__device__ __forceinline__ void rz_pk(f32x2& R, f32x2& I, f32x2 cc, f32x2 pzv) {
  const f32x2 nR = vfma(-pzv, I, cc * R);
  I = vfma(pzv, R, cc * I);
  R = nR;
}
template<int CTRL>
__device__ __forceinline__ void cnot_comm(f32x2& R, f32x2& I, bool sel) {
  const f32x2 tR = dpp2<CTRL>(R), tI = dpp2<CTRL>(I);
  R.x = sel ? tR.x : R.x; R.y = sel ? tR.y : R.y;
  I.x = sel ? tI.x : I.x; I.y = sel ? tI.y : I.y;
}
__device__ __forceinline__ void cnot23(f32x2& R, f32x2& I, bool sel) {
  const f32x2 sR = vswap(R), sI = vswap(I);
  R.x = sel ? sR.x : R.x; R.y = sel ? sR.y : R.y;
  I.x = sel ? sI.x : I.x; I.y = sel ? sI.y : I.y;
}

__global__ __launch_bounds__(256) void quanv_kernel(
    const float* __restrict__ x, const float* __restrict__ qp,
    __bf16* __restrict__ feats) {
  const int tid = threadIdx.x;
  const int l = tid & 63;
  const int wv = tid >> 6;
  const int sub = ((l >> 3) & 1) * 4 + ((l >> 1) & 1) * 2 + (l & 1);
  const int e = ((l >> 4) << 1) | ((l >> 2) & 1);
  const int b = blockIdx.x * 32 + wv * 8 + e;

  const float sg0 = ((l >> 3) & 1) ? 1.f : -1.f;
  const float sg1 = ((l >> 1) & 1) ? 1.f : -1.f;
  const float sg2 = (l & 1) ? 1.f : -1.f;
  const bool cn01 = ((l >> 3) & 1) != 0;
  const bool cn12 = ((l >> 1) & 1) != 0;
  const bool cn23 = (l & 1) != 0;
  const bool wen = (sub == 0) || (sub == 1) || (sub == 2) || (sub == 4);
  const int col = (sub == 4) ? 0 : (sub == 2) ? 1 : (sub == 1) ? 2 : 3;
  const bool use_e3 = (sub == 0);

  const float* xb = x + (size_t)b * 784;
  __bf16* fb = feats + (size_t)b * KFP;

  // fixed-gate packed constants (lane signs folded in)
  f32x2 ryc[8], rys[8], rzc[8], rzs[8];
#pragma unroll
  for (int g = 0; g < 8; g++) {
    const int w = g & 3;
    const float sgw = (w == 0) ? sg0 : (w == 1) ? sg1 : sg2;
    const float ta = qp[g * 2 + 0] * 0.5f;
    const float ca = cosf(ta), sa = sinf(ta);
    ryc[g] = splat(ca);
    rys[g] = (w == 3) ? mk2(-sa, sa) : splat(sgw * sa);
    const float tb = qp[g * 2 + 1] * 0.5f;
    const float cb = cosf(tb), sb = sinf(tb);
    rzc[g] = splat(cb);
    rzs[g] = (w == 3) ? mk2(-sb, sb) : splat(sgw * sb);
  }
  const f32x2 wc0 = mk2(-sg2, 1.f);
  const f32x2 wc1 = mk2(-sg1, 1.f);
  const f32x2 wc2 = mk2(-sg0, 1.f);

  f32x2 R = mk2((sub == 0) ? 1.f : 0.f, 0.f);
  f32x2 I = mk2(0.f, 0.f);

  float2 t0 = *(const float2*)(xb);
  float2 t1 = *(const float2*)(xb + 28);
  int nrr = 0, ncc = 0;

  for (int it = 0; it < 196; ++it) {
    // rolling prefetch of next patch
    int nc = ncc + 1, nr = nrr;
    if (nc == 14) { nc = 0; nr = nrr + 1; }
    const float* np = (it < 195) ? (xb + (2 * nr) * 28 + 2 * nc) : xb;
    const float2 n0 = *(const float2*)np;
    const float2 n1 = *(const float2*)(np + 28);

    // encode RY(v_w)
    float h, c_, s_;
    h = t0.x * 0.5f; c_ = __cosf(h); s_ = __sinf(h);
    ry_comm<ROR8>(R, I, splat(c_), splat(sg0 * s_));
    h = t0.y * 0.5f; c_ = __cosf(h); s_ = __sinf(h);
    ry_comm<XOR2>(R, I, splat(c_), splat(sg1 * s_));
    h = t1.x * 0.5f; c_ = __cosf(h); s_ = __sinf(h);
    ry_comm<XOR1>(R, I, splat(c_), splat(sg2 * s_));
    h = t1.y * 0.5f; c_ = __cosf(h); s_ = __sinf(h);
    ry_reg(R, I, splat(c_), mk2(-s_, s_));

#pragma unroll
    for (int ll = 0; ll < 2; ll++) {
      const int g0 = ll * 4;
      ry_comm<ROR8>(R, I, ryc[g0 + 0], rys[g0 + 0]);
      rz_pk(R, I, rzc[g0 + 0], rzs[g0 + 0]);
      ry_comm<XOR2>(R, I, ryc[g0 + 1], rys[g0 + 1]);
      rz_pk(R, I, rzc[g0 + 1], rzs[g0 + 1]);
      ry_comm<XOR1>(R, I, ryc[g0 + 2], rys[g0 + 2]);
      rz_pk(R, I, rzc[g0 + 2], rzs[g0 + 2]);
      ry_reg(R, I, ryc[g0 + 3], rys[g0 + 3]);
      rz_pk(R, I, rzc[g0 + 3], rzs[g0 + 3]);
      cnot_comm<XOR2>(R, I, cn01);   // CNOT(0,1)
      cnot_comm<XOR1>(R, I, cn12);   // CNOT(1,2)
      cnot23(R, I, cn23);            // CNOT(2,3)
    }

    // measure: packed (v,u) butterfly
    const f32x2 P = vfma(R, R, I * I);
    f32x2 w = mk2(P.x + P.y, P.x - P.y);
    w = vfma(wc0, w, dpp2<XOR1>(w));
    w = vfma(wc1, w, dpp2<XOR2>(w));
    w = vfma(wc2, w, dpp2<ROR8>(w));
    const float val = use_e3 ? w.y : w.x;
    if (wen) fb[it * 4 + col] = (__bf16)val;

    t0 = n0; t1 = n1; ncc = nc; nrr = nr;
  }

  // zero the K padding 784..800 (one designated lane per element)
  if (sub == 3) {
    const uint4 z = {0, 0, 0, 0};
    *(uint4*)(fb + 784) = z;
    *(uint4*)(fb + 792) = z;
  }
}

// =================== bf16 MFMA NT GEMM: C = A*B^T + bias ===================
// A: M x K bf16 (row-major, K%32==0), B: N x K bf16, C: M x N fp32.
// 128x64 tile, BK=32, 4 waves (2x2), double-buffered LDS via global_load_lds.
#define GBM 128
#define GBN 64
#define GBK 32

__device__ __forceinline__ void gld16(const void* g, void* l) {
  __builtin_amdgcn_global_load_lds(
      (const __attribute__((address_space(1))) unsigned int*)g,
      (__attribute__((address_space(3))) unsigned int*)l, 16, 0, 0);
}

__global__ __launch_bounds__(256) void gemm_bf16_nt(
    const __bf16* __restrict__ A, const __bf16* __restrict__ B,
    const float* __restrict__ bias, float* __restrict__ C,
    int M, int N, int K) {
  // LDS: As[2][128][64B] @0, Bs[2][64][64B] @16384. 16B chunks XOR-swizzled:
  // LDS[row][c] holds global chunk c ^ ((row>>1)&3).
  __shared__ char lds[24576];
  const int tid = threadIdx.x;
  const int bm = blockIdx.x * GBM;
  const int bn = blockIdx.y * GBN;
  const int NK = K / GBK;
  const size_t lda = (size_t)K * 2;

  // staging source addresses (per-lane; swizzle pre-applied to global chunk)
  const int srow = tid >> 2;           // 0..63
  const int lc16 = tid & 3;
  const int ag0 = lc16 ^ ((srow >> 1) & 3);
  const int ag1 = lc16 ^ (((srow + 64) >> 1) & 3);
  const char* a0p = (const char*)A + (size_t)(bm + srow) * lda + ag0 * 16;
  const char* a1p = (const char*)A + (size_t)(bm + 64 + srow) * lda + ag1 * 16;
  const char* b0p = (const char*)B + (size_t)(bn + srow) * lda + ag0 * 16;

  // fragment read offsets (swizzled), computed once
  const int wid = tid >> 6, lane = tid & 63;
  const int wr = wid >> 1, wc = wid & 1;
  const int ln15 = lane & 15, ln4 = lane >> 4;
  int aoff[4], boff[2];
#pragma unroll
  for (int m = 0; m < 4; m++) {
    const int row = wr * 64 + m * 16 + ln15;
    aoff[m] = row * 64 + ((ln4 ^ ((row >> 1) & 3)) * 16);
  }
#pragma unroll
  for (int n = 0; n < 2; n++) {
    const int row = wc * 32 + n * 16 + ln15;
    boff[n] = 16384 + row * 64 + ((ln4 ^ ((row >> 1) & 3)) * 16);
  }

  f32x4 acc[4][2];
#pragma unroll
  for (int m = 0; m < 4; m++)
#pragma unroll
    for (int n = 0; n < 2; n++) acc[m][n] = (f32x4){0.f, 0.f, 0.f, 0.f};

  // stage K-tile kt into buffer buf
  auto stage = [&](int buf, int kt) {
    const size_t kb = (size_t)kt * GBK * 2;
    char* as = lds + buf * 8192 + tid * 16;
    char* bs = lds + 16384 + buf * 4096 + tid * 16;
    gld16(a0p + kb, as);
    gld16(a1p + kb, as + 4096);
    gld16(b0p + kb, bs);
  };

  stage(0, 0);
  for (int kt = 0; kt < NK; kt++) {
    __syncthreads();                    // vmcnt drained -> buf[kt&1] ready
    if (kt + 1 < NK) stage((kt + 1) & 1, kt + 1);
    const int ab = (kt & 1) * 8192, bb = (kt & 1) * 4096;
    bf16x8 af[4], bfr[2];
#pragma unroll
    for (int m = 0; m < 4; m++) af[m] = *(const bf16x8*)(lds + ab + aoff[m]);
#pragma unroll
    for (int n = 0; n < 2; n++) bfr[n] = *(const bf16x8*)(lds + bb + boff[n]);
#pragma unroll
    for (int m = 0; m < 4; m++)
#pragma unroll
      for (int n = 0; n < 2; n++)
        acc[m][n] = __builtin_amdgcn_mfma_f32_16x16x32_bf16(af[m], bfr[n], acc[m][n], 0, 0, 0);
  }

  // epilogue: D layout col=lane&15, row=(lane>>4)*4+reg
#pragma unroll
  for (int n = 0; n < 2; n++) {
    const int ccol = bn + wc * 32 + n * 16 + ln15;
    const float bv = bias[ccol];
#pragma unroll
    for (int m = 0; m < 4; m++) {
      const int crow = bm + wr * 64 + m * 16 + ln4 * 4;
#pragma unroll
      for (int r = 0; r < 4; r++)
        C[(size_t)(crow + r) * N + ccol] = acc[m][n][r] + bv;
    }
  }
}

// ==================== weight conversion (fp32 -> bf16) =====================
__global__ __launch_bounds__(256) void cvt_pad_w1(const float* __restrict__ w,
                                                  __bf16* __restrict__ o) {
  const int r = blockIdx.x;   // 256 rows
  for (int c = threadIdx.x; c < KFP; c += 256)
    o[r * KFP + c] = (c < 784) ? (__bf16)w[r * 784 + c] : (__bf16)0.f;
}
__global__ __launch_bounds__(256) void cvt_w2(const float* __restrict__ w,
                                              __bf16* __restrict__ o) {
  const int i = blockIdx.x * 256 + threadIdx.x;
  o[i] = (__bf16)w[i];
}

// ======================= BatchNorm (training stats) ========================
__global__ __launch_bounds__(256) void bn_partial(const float* __restrict__ h,
                                                  float* __restrict__ partial) {
  const int blk = blockIdx.x;      // 256 blocks x 64 rows
  const int t = threadIdx.x;       // column
  const float* p = h + (size_t)blk * 64 * NH + t;
  float s = 0.f, ss = 0.f;
#pragma unroll 4
  for (int r = 0; r < 64; r++) {
    const float v = p[(size_t)r * NH];
    s += v; ss += v * v;
  }
  partial[blk * 512 + t] = s;
  partial[blk * 512 + 256 + t] = ss;
}

__global__ __launch_bounds__(256) void bn_finalize(
    const float* __restrict__ partial, const float* __restrict__ g,
    const float* __restrict__ be, float* __restrict__ ab, float* __restrict__ cb) {
  const int t = threadIdx.x;
  float s = 0.f, ss = 0.f;
  for (int i = 0; i < 256; i++) {
    s += partial[i * 512 + t];
    ss += partial[i * 512 + 256 + t];
  }
  const float mean = s * (1.f / 16384.f);
  const float var = ss * (1.f / 16384.f) - mean * mean;
  const float rstd = rsqrtf(var + 1e-5f);
  const float a = g[t] * rstd;
  ab[t] = a;
  cb[t] = be[t] - mean * a;
}

// BN+ReLU, writes fp32 in place and a bf16 copy (GEMM2 input)
__global__ __launch_bounds__(256) void bn_relu(float* __restrict__ h,
                                               __bf16* __restrict__ hb,
                                               const float* __restrict__ ab,
                                               const float* __restrict__ cb) {
  const size_t i = (size_t)blockIdx.x * 256 + threadIdx.x;  // float4 index
  float4 v = ((float4*)h)[i];
  const int col = (int)((i * 4) & (NH - 1));
  const float4 a = *(const float4*)(ab + col);
  const float4 c = *(const float4*)(cb + col);
  v.x = fmaxf(v.x * a.x + c.x, 0.f);
  v.y = fmaxf(v.y * a.y + c.y, 0.f);
  v.z = fmaxf(v.z * a.z + c.z, 0.f);
  v.w = fmaxf(v.w * a.w + c.w, 0.f);
  ((float4*)h)[i] = v;
  bf16x4 o = {(__bf16)v.x, (__bf16)v.y, (__bf16)v.z, (__bf16)v.w};
  *(bf16x4*)(hb + i * 4) = o;
}

__global__ __launch_bounds__(256) void bn_relu_res(float* __restrict__ h2,
                                                   const float* __restrict__ h1,
                                                   const float* __restrict__ ab,
                                                   const float* __restrict__ cb) {
  const size_t i = (size_t)blockIdx.x * 256 + threadIdx.x;
  float4 v = ((float4*)h2)[i];
  const float4 rsd = ((const float4*)h1)[i];
  const int col = (int)((i * 4) & (NH - 1));
  const float4 a = *(const float4*)(ab + col);
  const float4 c = *(const float4*)(cb + col);
  v.x = fmaxf(v.x * a.x + c.x, 0.f) + rsd.x;
  v.y = fmaxf(v.y * a.y + c.y, 0.f) + rsd.y;
  v.z = fmaxf(v.z * a.z + c.z, 0.f) + rsd.z;
  v.w = fmaxf(v.w * a.w + c.w, 0.f) + rsd.w;
  ((float4*)h2)[i] = v;
}

// ================ head: logits = h2 @ w3^T + b3, then log_softmax ==========
__global__ __launch_bounds__(256) void head_kernel(
    const float* __restrict__ h2, const float* __restrict__ w3,
    const float* __restrict__ b3, float* __restrict__ out) {
  __shared__ float w3s[NCLS * NH];
  for (int i = threadIdx.x; i < NCLS * NH; i += 256) w3s[i] = w3[i];
  __syncthreads();

  const int m = blockIdx.x * 256 + threadIdx.x;
  const float* hr = h2 + (size_t)m * NH;
  float acc[NCLS];
#pragma unroll
  for (int n = 0; n < NCLS; n++) acc[n] = b3[n];

  for (int k = 0; k < NH; k += 4) {
    const float4 hv = *(const float4*)(hr + k);
#pragma unroll
    for (int n = 0; n < NCLS; n++) {
      const float4 wv = *(const float4*)&w3s[n * NH + k];
      acc[n] += hv.x * wv.x + hv.y * wv.y + hv.z * wv.z + hv.w * wv.w;
    }
  }

  float mx = acc[0];
#pragma unroll
  for (int n = 1; n < NCLS; n++) mx = fmaxf(mx, acc[n]);
  float se = 0.f;
#pragma unroll
  for (int n = 0; n < NCLS; n++) se += expf(acc[n] - mx);
  const float lse = logf(se) + mx;
#pragma unroll
  for (int n = 0; n < NCLS; n++) out[(size_t)m * NCLS + n] = acc[n] - lse;
}

// =========================== launch ========================================
extern "C" void kernel_launch(void* const* d_in, const int* in_sizes, int n_in,
                              void* d_out, int out_size, void* d_ws, size_t ws_size,
                              hipStream_t stream) {
  const float* x   = (const float*)d_in[0];
  const float* qp  = (const float*)d_in[1];
  const float* w1  = (const float*)d_in[2];
  const float* b1  = (const float*)d_in[3];
  const float* g1  = (const float*)d_in[4];
  const float* be1 = (const float*)d_in[5];
  const float* w2  = (const float*)d_in[6];
  const float* b2  = (const float*)d_in[7];
  const float* g2  = (const float*)d_in[8];
  const float* be2 = (const float*)d_in[9];
  const float* w3  = (const float*)d_in[10];
  const float* b3  = (const float*)d_in[11];
  float* out = (float*)d_out;

  // workspace layout (bytes), total ~69.2 MB
  char* w = (char*)d_ws;
  __bf16* feats = (__bf16*)w;                         // 16384*800*2 = 26,214,400
  float*  h1    = (float*)(w + 26214400);             // 16,777,216
  float*  h2    = (float*)(w + 42991616);             // 16,777,216
  __bf16* h1b   = (__bf16*)(w + 59768832);            //  8,388,608
  __bf16* w1b   = (__bf16*)(w + 68157440);            //    409,600
  __bf16* w2b   = (__bf16*)(w + 68567040);            //    131,072
  float*  partial = (float*)(w + 68698112);           //    524,288
  float*  ab1   = (float*)(w + 69222400);
  float*  cb1   = (float*)(w + 69223424);
  float*  ab2   = (float*)(w + 69224448);
  float*  cb2   = (float*)(w + 69225472);

  cvt_pad_w1<<<256, 256, 0, stream>>>(w1, w1b);
  cvt_w2<<<256, 256, 0, stream>>>(w2, w2b);
  quanv_kernel<<<(BQ * 8) / 256, 256, 0, stream>>>(x, qp, feats);

  gemm_bf16_nt<<<dim3(BQ / GBM, NH / GBN), 256, 0, stream>>>(
      feats, w1b, b1, h1, BQ, NH, KFP);
  bn_partial<<<256, 256, 0, stream>>>(h1, partial);
  bn_finalize<<<1, 256, 0, stream>>>(partial, g1, be1, ab1, cb1);
  bn_relu<<<(BQ * NH / 4) / 256, 256, 0, stream>>>(h1, h1b, ab1, cb1);

  gemm_bf16_nt<<<dim3(BQ / GBM, NH / GBN), 256, 0, stream>>>(
      h1b, w2b, b2, h2, BQ, NH, NH);
  bn_partial<<<256, 256, 0, stream>>>(h2, partial);
  bn_finalize<<<1, 256, 0, stream>>>(partial, g2, be2, ab2, cb2);
  bn_relu_res<<<(BQ * NH / 4) / 256, 256, 0, stream>>>(h2, h1, ab2, cb2);

  head_kernel<<<BQ / 256, 256, 0, stream>>>(h2, w3, b3, out);
}

// Round 5
// 245.638 us; speedup vs baseline: 2.6686x; 1.1968x over previous
//
#include <hip/hip_runtime.h>
#include <math.h>

#define BQ 16384      // batch
#define KFP 800       // padded quanv feature dim (196*4 = 784, +16 zero pad)
#define NH 256        // hidden dim
#define NCLS 10

typedef float f32x2 __attribute__((ext_vector_type(2)));
typedef float f32x4 __attribute__((ext_vector_type(4)));
typedef __bf16 bf16x8 __attribute__((ext_vector_type(8)));
typedef __bf16 bf16x4 __attribute__((ext_vector_type(4)));
typedef __bf16 bf16x2 __attribute__((ext_vector_type(2)));

// ===================== build_U: compose the fixed 16x16 unitary ============
// Gate code verbatim from the round-0 verified scalar simulator.
// Amp index bits: wire w <-> bit (8>>w), matching reference flatten order.

template<int ST>
__device__ __forceinline__ void u_ry(float* sr, float* si, float c, float s) {
#pragma unroll
  for (int i = 0; i < 16; i++) {
    if (i & ST) continue;
    const int j = i | ST;
    const float a0r = sr[i], a0i = si[i], a1r = sr[j], a1i = si[j];
    sr[i] = c * a0r - s * a1r;  si[i] = c * a0i - s * a1i;
    sr[j] = s * a0r + c * a1r;  si[j] = s * a0i + c * a1i;
  }
}
template<int ST>
__device__ __forceinline__ void u_rz(float* sr, float* si, float c, float s) {
#pragma unroll
  for (int i = 0; i < 16; i++) {
    const float pz = (i & ST) ? s : -s;
    const float ar = sr[i], ai = si[i];
    sr[i] = c * ar - pz * ai;
    si[i] = c * ai + pz * ar;
  }
}
template<int SC, int STG>
__device__ __forceinline__ void u_cnot(float* sr, float* si) {
#pragma unroll
  for (int i = 0; i < 16; i++) {
    if (!(i & SC) || (i & STG)) continue;
    const int j = i | STG;
    float t;
    t = sr[i]; sr[i] = sr[j]; sr[j] = t;
    t = si[i]; si[i] = si[j]; si[j] = t;
  }
}

// Component space (5-bit index): comp(t, g, j): ReIm = g>>1, amp-bit layout:
//   a_w0 = g&1, a_w1 = t (acc chain), a_w2 = j>>1, a_w3 = j&1
//   amp = (g&1)*8 + t*4 + j
// D rows (chain t): row r = 4g + j -> comp(t, r): ri=(r>>3)&1,
//   amp=((r>>2)&1)*8 + t*4 + (r&3).
// B k-index: k = kg*8 + m -> comp(t=m>>2, g=kg, j=m&3).
// Abuf layout: flat f: m=f&7, row=(f>>3)&15, kg=(f>>7)&3, hl=(f>>9)&1, t=f>>10.

__global__ __launch_bounds__(256) void build_U(const float* __restrict__ qp,
                                               __bf16* __restrict__ Abuf) {
  __shared__ float Ur[16][16], Ui[16][16];
  const int tid = threadIdx.x;
  if (tid < 16) {
    float sr[16], si[16];
#pragma unroll
    for (int i = 0; i < 16; i++) { sr[i] = (i == tid) ? 1.f : 0.f; si[i] = 0.f; }
#pragma unroll
    for (int l = 0; l < 2; l++) {
      { const float t = qp[l*8 + 0] * 0.5f; u_ry<8>(sr, si, cosf(t), sinf(t)); }
      { const float t = qp[l*8 + 1] * 0.5f; u_rz<8>(sr, si, cosf(t), sinf(t)); }
      { const float t = qp[l*8 + 2] * 0.5f; u_ry<4>(sr, si, cosf(t), sinf(t)); }
      { const float t = qp[l*8 + 3] * 0.5f; u_rz<4>(sr, si, cosf(t), sinf(t)); }
      { const float t = qp[l*8 + 4] * 0.5f; u_ry<2>(sr, si, cosf(t), sinf(t)); }
      { const float t = qp[l*8 + 5] * 0.5f; u_rz<2>(sr, si, cosf(t), sinf(t)); }
      { const float t = qp[l*8 + 6] * 0.5f; u_ry<1>(sr, si, cosf(t), sinf(t)); }
      { const float t = qp[l*8 + 7] * 0.5f; u_rz<1>(sr, si, cosf(t), sinf(t)); }
      u_cnot<8, 4>(sr, si);
      u_cnot<4, 2>(sr, si);
      u_cnot<2, 1>(sr, si);
    }
#pragma unroll
    for (int r = 0; r < 16; r++) { Ur[r][tid] = sr[r]; Ui[r][tid] = si[r]; }
  }
  __syncthreads();
  for (int f = tid; f < 2048; f += 256) {
    const int m   = f & 7;
    const int row = (f >> 3) & 15;
    const int kg  = (f >> 7) & 3;
    const int hl  = (f >> 9) & 1;
    const int t   = (f >> 10) & 1;
    const int k   = kg * 8 + m;
    const int ri_o  = (row >> 3) & 1;
    const int amp_o = ((row >> 2) & 1) * 8 + t * 4 + (row & 3);
    const int ri_i  = (k >> 4) & 1;
    const int amp_i = ((k >> 3) & 1) * 8 + (m >> 2) * 4 + (m & 3);
    const float u_r = Ur[amp_o][amp_i], u_i = Ui[amp_o][amp_i];
    float v = (ri_o == 0) ? ((ri_i == 0) ? u_r : -u_i)
                          : ((ri_i == 0) ? u_i : u_r);
    if (hl) {
      const __bf16 hb = (__bf16)v;
      v = v - (float)hb;
    }
    Abuf[f] = (__bf16)v;
  }
}

// ======================= quanv via MFMA ====================================
// 16 elements/wave: col = lane&15, kg = lane>>4 (g0 = wire0 amp-bit,
// g1 = Re/Im). State = 2 acc chains (f32x4 each) = 8 comps/lane.
// Per patch: E (VALU butterflies, wire0 via ds_swizzle xor16) -> bf16 hi/lo
// split -> 6x mfma_f32_16x16x32_bf16 -> measure (tree + swizzle + bpermute).

__device__ __forceinline__ float swz16(float v) {
  return __int_as_float(__builtin_amdgcn_ds_swizzle(__float_as_int(v), 0x401F));
}

__global__ __launch_bounds__(256) void quanv_mfma(
    const float* __restrict__ x, const __bf16* __restrict__ Abuf,
    __bf16* __restrict__ feats) {
  const int tid = threadIdx.x;
  const int l = tid & 63;
  const int wv = tid >> 6;
  const int col = l & 15;
  const int kg = l >> 4;
  const int b = blockIdx.x * 64 + wv * 16 + col;
  const float* xb = x + (size_t)b * 784;
  __bf16* fb = feats + (size_t)b * KFP;
  const float sg0 = (kg & 1) ? 1.f : -1.f;       // wire0 amp-bit sign
  const int bpa = (l ^ 32) << 2;                 // ds_bpermute addr (xor32)

  // A fragments (held in VGPRs for the whole kernel)
  const bf16x8* Ab = (const bf16x8*)Abuf;
  const bf16x8 A0h = Ab[(0 * 4 + kg) * 16 + col];
  const bf16x8 A0l = Ab[(1 * 4 + kg) * 16 + col];
  const bf16x8 A1h = Ab[(2 * 4 + kg) * 16 + col];
  const bf16x8 A1l = Ab[(3 * 4 + kg) * 16 + col];

  // state |0000>: comp amp=0, Re -> chain0 reg0 at kg==0 lanes
  f32x4 c0 = {(kg == 0) ? 1.f : 0.f, 0.f, 0.f, 0.f};
  f32x4 c1 = {0.f, 0.f, 0.f, 0.f};
  const f32x4 z4 = {0.f, 0.f, 0.f, 0.f};

  float2 t0 = *(const float2*)(xb);
  float2 t1 = *(const float2*)(xb + 28);
  int nrr = 0, ncc = 0;

  for (int it = 0; it < 196; ++it) {
    // rolling prefetch of next patch
    int nc = ncc + 1, nr = nrr;
    if (nc == 14) { nc = 0; nr = nrr + 1; }
    const float* np = (it < 195) ? (xb + (2 * nr) * 28 + 2 * nc) : xb;
    const float2 n0 = *(const float2*)np;
    const float2 n1 = *(const float2*)(np + 28);

    // ---- E(vals): 4 RY butterflies on fp32 state ----
    const float h0 = t0.x * 0.5f, h1 = t0.y * 0.5f;
    const float h2 = t1.x * 0.5f, h3 = t1.y * 0.5f;
    const float cw0 = __cosf(h0), sw0 = __sinf(h0);
    const float cw1 = __cosf(h1), sw1 = __sinf(h1);
    const float cw2 = __cosf(h2), sw2 = __sinf(h2);
    const float cw3 = __cosf(h3), sw3 = __sinf(h3);

    float S[8] = {c0.x, c0.y, c0.z, c0.w, c1.x, c1.y, c1.z, c1.w};
    // wire1: chain pairs (S[j], S[4+j])
#pragma unroll
    for (int j = 0; j < 4; j++) {
      const float a = S[j];
      S[j]     = fmaf(-sw1, S[4 + j], cw1 * S[j]);
      S[4 + j] = fmaf( sw1, a,        cw1 * S[4 + j]);
    }
    // wire2: pairs (i, i^2) within chains
#pragma unroll
    for (int base = 0; base < 8; base += 4)
#pragma unroll
      for (int j = 0; j < 2; j++) {
        const int i0 = base + j, i1 = base + j + 2;
        const float a = S[i0];
        S[i0] = fmaf(-sw2, S[i1], cw2 * S[i0]);
        S[i1] = fmaf( sw2, a,     cw2 * S[i1]);
      }
    // wire3: pairs (i, i^1)
#pragma unroll
    for (int i0 = 0; i0 < 8; i0 += 2) {
      const float a = S[i0];
      S[i0]     = fmaf(-sw3, S[i0 + 1], cw3 * S[i0]);
      S[i0 + 1] = fmaf( sw3, a,         cw3 * S[i0 + 1]);
    }
    // wire0: cross-lane xor16 via ds_swizzle
    float P[8];
#pragma unroll
    for (int i = 0; i < 8; i++) P[i] = swz16(S[i]);
    const float ss0 = sg0 * sw0;
#pragma unroll
    for (int i = 0; i < 8; i++) S[i] = fmaf(ss0, P[i], cw0 * S[i]);

    // ---- split hi/lo and pack B fragments ----
    bf16x8 Bh, Bl;
#pragma unroll
    for (int i = 0; i < 8; i++) {
      const __bf16 hb = (__bf16)S[i];
      Bh[i] = hb;
      Bl[i] = (__bf16)(S[i] - (float)hb);
    }

    // ---- 6 MFMAs: state' = U * E(v) * state (split precision) ----
    c0 = __builtin_amdgcn_mfma_f32_16x16x32_bf16(A0h, Bh, z4, 0, 0, 0);
    c0 = __builtin_amdgcn_mfma_f32_16x16x32_bf16(A0l, Bh, c0, 0, 0, 0);
    c0 = __builtin_amdgcn_mfma_f32_16x16x32_bf16(A0h, Bl, c0, 0, 0, 0);
    c1 = __builtin_amdgcn_mfma_f32_16x16x32_bf16(A1h, Bh, z4, 0, 0, 0);
    c1 = __builtin_amdgcn_mfma_f32_16x16x32_bf16(A1l, Bh, c1, 0, 0, 0);
    c1 = __builtin_amdgcn_mfma_f32_16x16x32_bf16(A1h, Bl, c1, 0, 0, 0);

    // ---- measure <Z_w> on new state ----
    const float q0 = c0.x, q1 = c0.y, q2 = c0.z, q3 = c0.w;
    const float q4 = c1.x, q5 = c1.y, q6 = c1.z, q7 = c1.w;
    const float sq0 = q0 * q0, sq1 = q1 * q1, sq2 = q2 * q2, sq3 = q3 * q3;
    const float sq4 = q4 * q4, sq5 = q5 * q5, sq6 = q6 * q6, sq7 = q7 * q7;
    const float s01 = sq0 + sq1, s23 = sq2 + sq3, s45 = sq4 + sq5, s67 = sq6 + sq7;
    const float d01 = sq0 - sq1, d23 = sq2 - sq3, d45 = sq4 - sq5, d67 = sq6 - sq7;
    const float z3 = (d01 + d23) + (d45 + d67);          // sign by j0 (wire3)
    const float z2 = (s01 - s23) + (s45 - s67);          // sign by j1 (wire2)
    const float q03 = s01 + s23, q47 = s45 + s67;
    const float z1 = q03 - q47;                          // sign by chain (wire1)
    const float T  = q03 + q47;
    // reduce over lane-bit4 (wire0 amp-bit; signed for z0)
    const float z0h = sg0 * (swz16(T) - T);              // = sum (-1)^{g0} T
    const float z1h = z1 + swz16(z1);
    const float z2h = z2 + swz16(z2);
    const float z3h = z3 + swz16(z3);
    // combine Re+Im over lane-bit5 via ds_bpermute
    const float z0 = z0h + __int_as_float(__builtin_amdgcn_ds_bpermute(bpa, __float_as_int(z0h)));
    const float z1f = z1h + __int_as_float(__builtin_amdgcn_ds_bpermute(bpa, __float_as_int(z1h)));
    const float z2f = z2h + __int_as_float(__builtin_amdgcn_ds_bpermute(bpa, __float_as_int(z2h)));
    const float z3f = z3h + __int_as_float(__builtin_amdgcn_ds_bpermute(bpa, __float_as_int(z3h)));

    if (kg == 0) {
      bf16x4 o = {(__bf16)z0, (__bf16)z1f, (__bf16)z2f, (__bf16)z3f};
      *(bf16x4*)(fb + it * 4) = o;
    }

    t0 = n0; t1 = n1; ncc = nc; nrr = nr;
  }

  // zero the K padding 784..800
  if (kg == 0) {
    *(uint4*)(fb + 784) = (uint4){0, 0, 0, 0};
    *(uint4*)(fb + 792) = (uint4){0, 0, 0, 0};
  }
}

// =================== bf16 MFMA NT GEMM: C = A*B^T + bias ===================
#define GBM 128
#define GBN 64
#define GBK 32

__device__ __forceinline__ void gld16(const void* g, void* l) {
  __builtin_amdgcn_global_load_lds(
      (const __attribute__((address_space(1))) unsigned int*)g,
      (__attribute__((address_space(3))) unsigned int*)l, 16, 0, 0);
}

__global__ __launch_bounds__(256) void gemm_bf16_nt(
    const __bf16* __restrict__ A, const __bf16* __restrict__ B,
    const float* __restrict__ bias, float* __restrict__ C,
    int M, int N, int K) {
  __shared__ char lds[24576];
  const int tid = threadIdx.x;
  const int bm = blockIdx.x * GBM;
  const int bn = blockIdx.y * GBN;
  const int NK = K / GBK;
  const size_t lda = (size_t)K * 2;

  const int srow = tid >> 2;
  const int lc16 = tid & 3;
  const int ag0 = lc16 ^ ((srow >> 1) & 3);
  const int ag1 = lc16 ^ (((srow + 64) >> 1) & 3);
  const char* a0p = (const char*)A + (size_t)(bm + srow) * lda + ag0 * 16;
  const char* a1p = (const char*)A + (size_t)(bm + 64 + srow) * lda + ag1 * 16;
  const char* b0p = (const char*)B + (size_t)(bn + srow) * lda + ag0 * 16;

  const int wid = tid >> 6, lane = tid & 63;
  const int wr = wid >> 1, wc = wid & 1;
  const int ln15 = lane & 15, ln4 = lane >> 4;
  int aoff[4], boff[2];
#pragma unroll
  for (int m = 0; m < 4; m++) {
    const int row = wr * 64 + m * 16 + ln15;
    aoff[m] = row * 64 + ((ln4 ^ ((row >> 1) & 3)) * 16);
  }
#pragma unroll
  for (int n = 0; n < 2; n++) {
    const int row = wc * 32 + n * 16 + ln15;
    boff[n] = 16384 + row * 64 + ((ln4 ^ ((row >> 1) & 3)) * 16);
  }

  f32x4 acc[4][2];
#pragma unroll
  for (int m = 0; m < 4; m++)
#pragma unroll
    for (int n = 0; n < 2; n++) acc[m][n] = (f32x4){0.f, 0.f, 0.f, 0.f};

  auto stage = [&](int buf, int kt) {
    const size_t kb = (size_t)kt * GBK * 2;
    char* as = lds + buf * 8192 + tid * 16;
    char* bs = lds + 16384 + buf * 4096 + tid * 16;
    gld16(a0p + kb, as);
    gld16(a1p + kb, as + 4096);
    gld16(b0p + kb, bs);
  };

  stage(0, 0);
  for (int kt = 0; kt < NK; kt++) {
    __syncthreads();
    if (kt + 1 < NK) stage((kt + 1) & 1, kt + 1);
    const int ab = (kt & 1) * 8192, bb = (kt & 1) * 4096;
    bf16x8 af[4], bfr[2];
#pragma unroll
    for (int m = 0; m < 4; m++) af[m] = *(const bf16x8*)(lds + ab + aoff[m]);
#pragma unroll
    for (int n = 0; n < 2; n++) bfr[n] = *(const bf16x8*)(lds + bb + boff[n]);
#pragma unroll
    for (int m = 0; m < 4; m++)
#pragma unroll
      for (int n = 0; n < 2; n++)
        acc[m][n] = __builtin_amdgcn_mfma_f32_16x16x32_bf16(af[m], bfr[n], acc[m][n], 0, 0, 0);
  }

#pragma unroll
  for (int n = 0; n < 2; n++) {
    const int ccol = bn + wc * 32 + n * 16 + ln15;
    const float bv = bias[ccol];
#pragma unroll
    for (int m = 0; m < 4; m++) {
      const int crow = bm + wr * 64 + m * 16 + ln4 * 4;
#pragma unroll
      for (int r = 0; r < 4; r++)
        C[(size_t)(crow + r) * N + ccol] = acc[m][n][r] + bv;
    }
  }
}

// ==================== weight conversion (fp32 -> bf16) =====================
__global__ __launch_bounds__(256) void cvt_pad_w1(const float* __restrict__ w,
                                                  __bf16* __restrict__ o) {
  const int r = blockIdx.x;
  for (int c = threadIdx.x; c < KFP; c += 256)
    o[r * KFP + c] = (c < 784) ? (__bf16)w[r * 784 + c] : (__bf16)0.f;
}
__global__ __launch_bounds__(256) void cvt_w2(const float* __restrict__ w,
                                              __bf16* __restrict__ o) {
  const int i = blockIdx.x * 256 + threadIdx.x;
  o[i] = (__bf16)w[i];
}

// ======================= BatchNorm (training stats) ========================
__global__ __launch_bounds__(256) void bn_partial(const float* __restrict__ h,
                                                  float* __restrict__ partial) {
  const int blk = blockIdx.x;
  const int t = threadIdx.x;
  const float* p = h + (size_t)blk * 64 * NH + t;
  float s = 0.f, ss = 0.f;
#pragma unroll 4
  for (int r = 0; r < 64; r++) {
    const float v = p[(size_t)r * NH];
    s += v; ss += v * v;
  }
  partial[blk * 512 + t] = s;
  partial[blk * 512 + 256 + t] = ss;
}

__global__ __launch_bounds__(256) void bn_finalize(
    const float* __restrict__ partial, const float* __restrict__ g,
    const float* __restrict__ be, float* __restrict__ ab, float* __restrict__ cb) {
  const int t = threadIdx.x;
  float s = 0.f, ss = 0.f;
  for (int i = 0; i < 256; i++) {
    s += partial[i * 512 + t];
    ss += partial[i * 512 + 256 + t];
  }
  const float mean = s * (1.f / 16384.f);
  const float var = ss * (1.f / 16384.f) - mean * mean;
  const float rstd = rsqrtf(var + 1e-5f);
  const float a = g[t] * rstd;
  ab[t] = a;
  cb[t] = be[t] - mean * a;
}

__global__ __launch_bounds__(256) void bn_relu(float* __restrict__ h,
                                               __bf16* __restrict__ hb,
                                               const float* __restrict__ ab,
                                               const float* __restrict__ cb) {
  const size_t i = (size_t)blockIdx.x * 256 + threadIdx.x;
  float4 v = ((float4*)h)[i];
  const int col = (int)((i * 4) & (NH - 1));
  const float4 a = *(const float4*)(ab + col);
  const float4 c = *(const float4*)(cb + col);
  v.x = fmaxf(v.x * a.x + c.x, 0.f);
  v.y = fmaxf(v.y * a.y + c.y, 0.f);
  v.z = fmaxf(v.z * a.z + c.z, 0.f);
  v.w = fmaxf(v.w * a.w + c.w, 0.f);
  ((float4*)h)[i] = v;
  bf16x4 o = {(__bf16)v.x, (__bf16)v.y, (__bf16)v.z, (__bf16)v.w};
  *(bf16x4*)(hb + i * 4) = o;
}

__global__ __launch_bounds__(256) void bn_relu_res(float* __restrict__ h2,
                                                   const float* __restrict__ h1,
                                                   const float* __restrict__ ab,
                                                   const float* __restrict__ cb) {
  const size_t i = (size_t)blockIdx.x * 256 + threadIdx.x;
  float4 v = ((float4*)h2)[i];
  const float4 rsd = ((const float4*)h1)[i];
  const int col = (int)((i * 4) & (NH - 1));
  const float4 a = *(const float4*)(ab + col);
  const float4 c = *(const float4*)(cb + col);
  v.x = fmaxf(v.x * a.x + c.x, 0.f) + rsd.x;
  v.y = fmaxf(v.y * a.y + c.y, 0.f) + rsd.y;
  v.z = fmaxf(v.z * a.z + c.z, 0.f) + rsd.z;
  v.w = fmaxf(v.w * a.w + c.w, 0.f) + rsd.w;
  ((float4*)h2)[i] = v;
}

// ================ head: logits = h2 @ w3^T + b3, then log_softmax ==========
__global__ __launch_bounds__(256) void head_kernel(
    const float* __restrict__ h2, const float* __restrict__ w3,
    const float* __restrict__ b3, float* __restrict__ out) {
  __shared__ float w3s[NCLS * NH];
  for (int i = threadIdx.x; i < NCLS * NH; i += 256) w3s[i] = w3[i];
  __syncthreads();

  const int m = blockIdx.x * 256 + threadIdx.x;
  const float* hr = h2 + (size_t)m * NH;
  float acc[NCLS];
#pragma unroll
  for (int n = 0; n < NCLS; n++) acc[n] = b3[n];

  for (int k = 0; k < NH; k += 4) {
    const float4 hv = *(const float4*)(hr + k);
#pragma unroll
    for (int n = 0; n < NCLS; n++) {
      const float4 wv = *(const float4*)&w3s[n * NH + k];
      acc[n] += hv.x * wv.x + hv.y * wv.y + hv.z * wv.z + hv.w * wv.w;
    }
  }

  float mx = acc[0];
#pragma unroll
  for (int n = 1; n < NCLS; n++) mx = fmaxf(mx, acc[n]);
  float se = 0.f;
#pragma unroll
  for (int n = 0; n < NCLS; n++) se += expf(acc[n] - mx);
  const float lse = logf(se) + mx;
#pragma unroll
  for (int n = 0; n < NCLS; n++) out[(size_t)m * NCLS + n] = acc[n] - lse;
}

// =========================== launch ========================================
extern "C" void kernel_launch(void* const* d_in, const int* in_sizes, int n_in,
                              void* d_out, int out_size, void* d_ws, size_t ws_size,
                              hipStream_t stream) {
  const float* x   = (const float*)d_in[0];
  const float* qp  = (const float*)d_in[1];
  const float* w1  = (const float*)d_in[2];
  const float* b1  = (const float*)d_in[3];
  const float* g1  = (const float*)d_in[4];
  const float* be1 = (const float*)d_in[5];
  const float* w2  = (const float*)d_in[6];
  const float* b2  = (const float*)d_in[7];
  const float* g2  = (const float*)d_in[8];
  const float* be2 = (const float*)d_in[9];
  const float* w3  = (const float*)d_in[10];
  const float* b3  = (const float*)d_in[11];
  float* out = (float*)d_out;

  char* w = (char*)d_ws;
  __bf16* feats = (__bf16*)w;                         // 26,214,400
  float*  h1    = (float*)(w + 26214400);             // 16,777,216
  float*  h2    = (float*)(w + 42991616);             // 16,777,216
  __bf16* h1b   = (__bf16*)(w + 59768832);            //  8,388,608
  __bf16* w1b   = (__bf16*)(w + 68157440);            //    409,600
  __bf16* w2b   = (__bf16*)(w + 68567040);            //    131,072
  float*  partial = (float*)(w + 68698112);           //    524,288
  float*  ab1   = (float*)(w + 69222400);
  float*  cb1   = (float*)(w + 69223424);
  float*  ab2   = (float*)(w + 69224448);
  float*  cb2   = (float*)(w + 69225472);
  __bf16* Abuf  = (__bf16*)(w + 69226496);            //      4,096

  build_U<<<1, 256, 0, stream>>>(qp, Abuf);
  cvt_pad_w1<<<256, 256, 0, stream>>>(w1, w1b);
  cvt_w2<<<256, 256, 0, stream>>>(w2, w2b);

  quanv_mfma<<<BQ / 64, 256, 0, stream>>>(x, Abuf, feats);

  gemm_bf16_nt<<<dim3(BQ / GBM, NH / GBN), 256, 0, stream>>>(
      feats, w1b, b1, h1, BQ, NH, KFP);
  bn_partial<<<256, 256, 0, stream>>>(h1, partial);
  bn_finalize<<<1, 256, 0, stream>>>(partial, g1, be1, ab1, cb1);
  bn_relu<<<(BQ * NH / 4) / 256, 256, 0, stream>>>(h1, h1b, ab1, cb1);

  gemm_bf16_nt<<<dim3(BQ / GBM, NH / GBN), 256, 0, stream>>>(
      h1b, w2b, b2, h2, BQ, NH, NH);
  bn_partial<<<256, 256, 0, stream>>>(h2, partial);
  bn_finalize<<<1, 256, 0, stream>>>(partial, g2, be2, ab2, cb2);
  bn_relu_res<<<(BQ * NH / 4) / 256, 256, 0, stream>>>(h2, h1, ab2, cb2);

  head_kernel<<<BQ / 256, 256, 0, stream>>>(h2, w3, b3, out);
}

// Round 6
// 228.784 us; speedup vs baseline: 2.8652x; 1.0737x over previous
//
#include <hip/hip_runtime.h>
#include <math.h>

#define BQ 16384      // batch
#define KFP 800       // padded quanv feature dim (196*4 = 784, +16 zero pad)
#define NH 256        // hidden dim
#define NCLS 10

typedef float f32x2 __attribute__((ext_vector_type(2)));
typedef float f32x4 __attribute__((ext_vector_type(4)));
typedef unsigned int u32x2 __attribute__((ext_vector_type(2)));
typedef __bf16 bf16x8 __attribute__((ext_vector_type(8)));
typedef __bf16 bf16x4 __attribute__((ext_vector_type(4)));

// ===================== build_U: compose the fixed 16x16 unitary ============
// Amp index bits: wire w <-> bit (8>>w), matching reference flatten order.
// Component index k (B/K-dim): b4=w0, b3=ReIm, b2..b0 = (w1,w2,w3)
//   k = kg*8 + m, kg = (w0, ReIm), m = w1*4 + w2*2 + w3
// D row r (per chain t=w1): r = kg*4 + j -> w0=(r>>3), ReIm=(r>>2)&1, (w2,w3)=j

template<int ST>
__device__ __forceinline__ void u_ry(float* sr, float* si, float c, float s) {
#pragma unroll
  for (int i = 0; i < 16; i++) {
    if (i & ST) continue;
    const int j = i | ST;
    const float a0r = sr[i], a0i = si[i], a1r = sr[j], a1i = si[j];
    sr[i] = c * a0r - s * a1r;  si[i] = c * a0i - s * a1i;
    sr[j] = s * a0r + c * a1r;  si[j] = s * a0i + c * a1i;
  }
}
template<int ST>
__device__ __forceinline__ void u_rz(float* sr, float* si, float c, float s) {
#pragma unroll
  for (int i = 0; i < 16; i++) {
    const float pz = (i & ST) ? s : -s;
    const float ar = sr[i], ai = si[i];
    sr[i] = c * ar - pz * ai;
    si[i] = c * ai + pz * ar;
  }
}
template<int SC, int STG>
__device__ __forceinline__ void u_cnot(float* sr, float* si) {
#pragma unroll
  for (int i = 0; i < 16; i++) {
    if (!(i & SC) || (i & STG)) continue;
    const int j = i | STG;
    float t;
    t = sr[i]; sr[i] = sr[j]; sr[j] = t;
    t = si[i]; si[i] = si[j]; si[j] = t;
  }
}

__global__ __launch_bounds__(256) void build_U(const float* __restrict__ qp,
                                               __bf16* __restrict__ Abuf) {
  __shared__ float Ur[16][16], Ui[16][16];
  const int tid = threadIdx.x;
  if (tid < 16) {
    float sr[16], si[16];
#pragma unroll
    for (int i = 0; i < 16; i++) { sr[i] = (i == tid) ? 1.f : 0.f; si[i] = 0.f; }
#pragma unroll
    for (int l = 0; l < 2; l++) {
      { const float t = qp[l*8 + 0] * 0.5f; u_ry<8>(sr, si, cosf(t), sinf(t)); }
      { const float t = qp[l*8 + 1] * 0.5f; u_rz<8>(sr, si, cosf(t), sinf(t)); }
      { const float t = qp[l*8 + 2] * 0.5f; u_ry<4>(sr, si, cosf(t), sinf(t)); }
      { const float t = qp[l*8 + 3] * 0.5f; u_rz<4>(sr, si, cosf(t), sinf(t)); }
      { const float t = qp[l*8 + 4] * 0.5f; u_ry<2>(sr, si, cosf(t), sinf(t)); }
      { const float t = qp[l*8 + 5] * 0.5f; u_rz<2>(sr, si, cosf(t), sinf(t)); }
      { const float t = qp[l*8 + 6] * 0.5f; u_ry<1>(sr, si, cosf(t), sinf(t)); }
      { const float t = qp[l*8 + 7] * 0.5f; u_rz<1>(sr, si, cosf(t), sinf(t)); }
      u_cnot<8, 4>(sr, si);
      u_cnot<4, 2>(sr, si);
      u_cnot<2, 1>(sr, si);
    }
#pragma unroll
    for (int r = 0; r < 16; r++) { Ur[r][tid] = sr[r]; Ui[r][tid] = si[r]; }
  }
  __syncthreads();
  for (int f = tid; f < 2048; f += 256) {
    const int m   = f & 7;
    const int row = (f >> 3) & 15;
    const int kg  = (f >> 7) & 3;
    const int hl  = (f >> 9) & 1;
    const int t   = (f >> 10) & 1;
    const int k   = kg * 8 + m;
    // NEW mapping: bit5=w0, bit4=ReIm  ->  row bit3=w0, bit2=ReIm; k bit4=w0, bit3=ReIm
    const int ri_o  = (row >> 2) & 1;
    const int amp_o = ((row >> 3) & 1) * 8 + t * 4 + (row & 3);
    const int ri_i  = (k >> 3) & 1;
    const int amp_i = ((k >> 4) & 1) * 8 + (m >> 2) * 4 + (m & 3);
    const float u_r = Ur[amp_o][amp_i], u_i = Ui[amp_o][amp_i];
    float v = (ri_o == 0) ? ((ri_i == 0) ? u_r : -u_i)
                          : ((ri_i == 0) ? u_i : u_r);
    if (hl) {
      const __bf16 hb = (__bf16)v;
      v = v - (float)hb;
    }
    Abuf[f] = (__bf16)v;
  }
}

// ======================= quanv via MFMA ====================================
// 16 elements/wave: col = lane&15, kg = lane>>4; b5 = w0 amp-bit, b4 = ReIm.
// E: wires 1-3 register-local; wire0 = permlane32_swap (VALU, no LDS).
// Measurement deferred one iteration (overlaps next patch's E).

__device__ __forceinline__ float swz16(float v) {
  return __int_as_float(__builtin_amdgcn_ds_swizzle(__float_as_int(v), 0x401F));
}
__device__ __forceinline__ float pl32(float v, bool r0sel) {
  const u32x2 r = __builtin_amdgcn_permlane32_swap(
      __float_as_uint(v), __float_as_uint(v), false, false);
  return __uint_as_float(r0sel ? r.x : r.y);
}

__global__ __launch_bounds__(256) void quanv_mfma(
    const float* __restrict__ x, const __bf16* __restrict__ Abuf,
    __bf16* __restrict__ feats) {
  const int tid = threadIdx.x;
  const int l = tid & 63;
  const int wv = tid >> 6;
  const int col = l & 15;
  const int kg = l >> 4;
  const int b = blockIdx.x * 64 + wv * 16 + col;
  const float* xb = x + (size_t)b * 784;
  __bf16* fb = feats + (size_t)b * KFP;
  const float sg0 = (l & 32) ? 1.f : -1.f;   // wire0 amp-bit sign (b5)

  // permlane32 partner-selection mask (robust to operand-swap semantics)
  const u32x2 pt = __builtin_amdgcn_permlane32_swap((unsigned)l, (unsigned)l,
                                                    false, false);
  const bool p32r0 = (pt.x == (unsigned)(l ^ 32));

  // A fragments (held in VGPRs for the whole kernel)
  const bf16x8* Ab = (const bf16x8*)Abuf;
  const bf16x8 A0h = Ab[(0 * 4 + kg) * 16 + col];
  const bf16x8 A0l = Ab[(1 * 4 + kg) * 16 + col];
  const bf16x8 A1h = Ab[(2 * 4 + kg) * 16 + col];
  const bf16x8 A1l = Ab[(3 * 4 + kg) * 16 + col];

  f32x4 c0 = {(kg == 0) ? 1.f : 0.f, 0.f, 0.f, 0.f};
  f32x4 c1 = {0.f, 0.f, 0.f, 0.f};
  const f32x4 z4 = {0.f, 0.f, 0.f, 0.f};

  // measurement of current state -> store 4 bf16 (lane kg==0)
  auto meas = [&](__bf16* dst) {
    const float sq0 = c0.x * c0.x, sq1 = c0.y * c0.y;
    const float sq2 = c0.z * c0.z, sq3 = c0.w * c0.w;
    const float sq4 = c1.x * c1.x, sq5 = c1.y * c1.y;
    const float sq6 = c1.z * c1.z, sq7 = c1.w * c1.w;
    const float s01 = sq0 + sq1, s23 = sq2 + sq3;
    const float s45 = sq4 + sq5, s67 = sq6 + sq7;
    const float d01 = sq0 - sq1, d23 = sq2 - sq3;
    const float d45 = sq4 - sq5, d67 = sq6 - sq7;
    const float z3 = (d01 + d23) + (d45 + d67);   // sign by w3
    const float z2 = (s01 - s23) + (s45 - s67);   // sign by w2
    const float q03 = s01 + s23, q47 = s45 + s67;
    const float z1 = q03 - q47;                   // sign by w1 (chain)
    const float T  = q03 + q47;
    // ReIm combine over bit4 (ds_swizzle xor16; off critical path)
    const float z3a = z3 + swz16(z3);
    const float z2a = z2 + swz16(z2);
    const float z1a = z1 + swz16(z1);
    const float Ta  = T + swz16(T);
    // w0 combine over bit5 (permlane, VALU)
    const float z3f = z3a + pl32(z3a, p32r0);
    const float z2f = z2a + pl32(z2a, p32r0);
    const float z1f = z1a + pl32(z1a, p32r0);
    const float z0f = sg0 * (pl32(Ta, p32r0) - Ta);
    if (kg == 0) {
      bf16x4 o = {(__bf16)z0f, (__bf16)z1f, (__bf16)z2f, (__bf16)z3f};
      *(bf16x4*)dst = o;
    }
  };

  // E(vals) + 6 MFMAs (depth-2 chains)
  auto step = [&](float2 t0, float2 t1) {
    const float h0 = t0.x * 0.5f, h1 = t0.y * 0.5f;
    const float h2 = t1.x * 0.5f, h3 = t1.y * 0.5f;
    const float cw0 = __cosf(h0), sw0 = __sinf(h0);
    const float cw1 = __cosf(h1), sw1 = __sinf(h1);
    const float cw2 = __cosf(h2), sw2 = __sinf(h2);
    const float cw3 = __cosf(h3), sw3 = __sinf(h3);

    float S[8] = {c0.x, c0.y, c0.z, c0.w, c1.x, c1.y, c1.z, c1.w};
    // wire1: pairs (i, i^4)
#pragma unroll
    for (int j = 0; j < 4; j++) {
      const float a = S[j];
      S[j]     = fmaf(-sw1, S[4 + j], cw1 * S[j]);
      S[4 + j] = fmaf( sw1, a,        cw1 * S[4 + j]);
    }
    // wire2: pairs (i, i^2)
#pragma unroll
    for (int base = 0; base < 8; base += 4)
#pragma unroll
      for (int j = 0; j < 2; j++) {
        const int i0 = base + j, i1 = base + j + 2;
        const float a = S[i0];
        S[i0] = fmaf(-sw2, S[i1], cw2 * S[i0]);
        S[i1] = fmaf( sw2, a,     cw2 * S[i1]);
      }
    // wire3: pairs (i, i^1)
#pragma unroll
    for (int i0 = 0; i0 < 8; i0 += 2) {
      const float a = S[i0];
      S[i0]     = fmaf(-sw3, S[i0 + 1], cw3 * S[i0]);
      S[i0 + 1] = fmaf( sw3, a,         cw3 * S[i0 + 1]);
    }
    // wire0: cross-lane bit5 via permlane32 (VALU)
    float P[8];
#pragma unroll
    for (int i = 0; i < 8; i++) P[i] = pl32(S[i], p32r0);
    const float ss0 = sg0 * sw0;
#pragma unroll
    for (int i = 0; i < 8; i++) S[i] = fmaf(ss0, P[i], cw0 * S[i]);

    // split hi/lo, pack B fragments
    bf16x8 Bh, Bl;
#pragma unroll
    for (int i = 0; i < 8; i++) {
      const __bf16 hb = (__bf16)S[i];
      Bh[i] = hb;
      Bl[i] = (__bf16)(S[i] - (float)hb);
    }

    // 6 MFMAs, two independent depth-2 chains per output
    f32x4 p0 = __builtin_amdgcn_mfma_f32_16x16x32_bf16(A0h, Bh, z4, 0, 0, 0);
    f32x4 q0 = __builtin_amdgcn_mfma_f32_16x16x32_bf16(A0l, Bh, z4, 0, 0, 0);
    q0 = __builtin_amdgcn_mfma_f32_16x16x32_bf16(A0h, Bl, q0, 0, 0, 0);
    f32x4 p1 = __builtin_amdgcn_mfma_f32_16x16x32_bf16(A1h, Bh, z4, 0, 0, 0);
    f32x4 q1 = __builtin_amdgcn_mfma_f32_16x16x32_bf16(A1l, Bh, z4, 0, 0, 0);
    q1 = __builtin_amdgcn_mfma_f32_16x16x32_bf16(A1h, Bl, q1, 0, 0, 0);
    c0 = p0 + q0;
    c1 = p1 + q1;
  };

  // ---- iteration 0 (no pending measurement) ----
  float2 t0 = *(const float2*)(xb);
  float2 t1 = *(const float2*)(xb + 28);
  int nrr = 0, ncc = 0;
  {
    const float2 n0 = *(const float2*)(xb + 2);
    const float2 n1 = *(const float2*)(xb + 30);
    step(t0, t1);
    t0 = n0; t1 = n1; ncc = 1; nrr = 0;
  }
  // ---- iterations 1..195: measure prev state (deferred) + step ----
  for (int it = 1; it < 196; ++it) {
    int nc = ncc + 1, nr = nrr;
    if (nc == 14) { nc = 0; nr = nrr + 1; }
    const float* np = (it < 195) ? (xb + (2 * nr) * 28 + 2 * nc) : xb;
    const float2 n0 = *(const float2*)np;
    const float2 n1 = *(const float2*)(np + 28);

    meas(fb + (it - 1) * 4);   // measurement of S_{it-1}, overlaps E below
    step(t0, t1);

    t0 = n0; t1 = n1; ncc = nc; nrr = nr;
  }
  meas(fb + 195 * 4);

  // zero the K padding 784..800
  if (kg == 0) {
    *(uint4*)(fb + 784) = (uint4){0, 0, 0, 0};
    *(uint4*)(fb + 792) = (uint4){0, 0, 0, 0};
  }
}

// =================== bf16 MFMA NT GEMM: C = A*B^T + bias ===================
#define GBM 128
#define GBN 64
#define GBK 32

__device__ __forceinline__ void gld16(const void* g, void* l) {
  __builtin_amdgcn_global_load_lds(
      (const __attribute__((address_space(1))) unsigned int*)g,
      (__attribute__((address_space(3))) unsigned int*)l, 16, 0, 0);
}

__global__ __launch_bounds__(256) void gemm_bf16_nt(
    const __bf16* __restrict__ A, const __bf16* __restrict__ B,
    const float* __restrict__ bias, float* __restrict__ C,
    int M, int N, int K) {
  __shared__ char lds[24576];
  const int tid = threadIdx.x;
  const int bm = blockIdx.x * GBM;
  const int bn = blockIdx.y * GBN;
  const int NK = K / GBK;
  const size_t lda = (size_t)K * 2;

  const int srow = tid >> 2;
  const int lc16 = tid & 3;
  const int ag0 = lc16 ^ ((srow >> 1) & 3);
  const int ag1 = lc16 ^ (((srow + 64) >> 1) & 3);
  const char* a0p = (const char*)A + (size_t)(bm + srow) * lda + ag0 * 16;
  const char* a1p = (const char*)A + (size_t)(bm + 64 + srow) * lda + ag1 * 16;
  const char* b0p = (const char*)B + (size_t)(bn + srow) * lda + ag0 * 16;

  const int wid = tid >> 6, lane = tid & 63;
  const int wr = wid >> 1, wc = wid & 1;
  const int ln15 = lane & 15, ln4 = lane >> 4;
  int aoff[4], boff[2];
#pragma unroll
  for (int m = 0; m < 4; m++) {
    const int row = wr * 64 + m * 16 + ln15;
    aoff[m] = row * 64 + ((ln4 ^ ((row >> 1) & 3)) * 16);
  }
#pragma unroll
  for (int n = 0; n < 2; n++) {
    const int row = wc * 32 + n * 16 + ln15;
    boff[n] = 16384 + row * 64 + ((ln4 ^ ((row >> 1) & 3)) * 16);
  }

  f32x4 acc[4][2];
#pragma unroll
  for (int m = 0; m < 4; m++)
#pragma unroll
    for (int n = 0; n < 2; n++) acc[m][n] = (f32x4){0.f, 0.f, 0.f, 0.f};

  auto stage = [&](int buf, int kt) {
    const size_t kb = (size_t)kt * GBK * 2;
    char* as = lds + buf * 8192 + tid * 16;
    char* bs = lds + 16384 + buf * 4096 + tid * 16;
    gld16(a0p + kb, as);
    gld16(a1p + kb, as + 4096);
    gld16(b0p + kb, bs);
  };

  stage(0, 0);
  for (int kt = 0; kt < NK; kt++) {
    __syncthreads();
    if (kt + 1 < NK) stage((kt + 1) & 1, kt + 1);
    const int ab = (kt & 1) * 8192, bb = (kt & 1) * 4096;
    bf16x8 af[4], bfr[2];
#pragma unroll
    for (int m = 0; m < 4; m++) af[m] = *(const bf16x8*)(lds + ab + aoff[m]);
#pragma unroll
    for (int n = 0; n < 2; n++) bfr[n] = *(const bf16x8*)(lds + bb + boff[n]);
#pragma unroll
    for (int m = 0; m < 4; m++)
#pragma unroll
      for (int n = 0; n < 2; n++)
        acc[m][n] = __builtin_amdgcn_mfma_f32_16x16x32_bf16(af[m], bfr[n], acc[m][n], 0, 0, 0);
  }

#pragma unroll
  for (int n = 0; n < 2; n++) {
    const int ccol = bn + wc * 32 + n * 16 + ln15;
    const float bv = bias[ccol];
#pragma unroll
    for (int m = 0; m < 4; m++) {
      const int crow = bm + wr * 64 + m * 16 + ln4 * 4;
#pragma unroll
      for (int r = 0; r < 4; r++)
        C[(size_t)(crow + r) * N + ccol] = acc[m][n][r] + bv;
    }
  }
}

// ==================== weight conversion (fp32 -> bf16) =====================
__global__ __launch_bounds__(256) void cvt_pad_w1(const float* __restrict__ w,
                                                  __bf16* __restrict__ o) {
  const int r = blockIdx.x;
  for (int c = threadIdx.x; c < KFP; c += 256)
    o[r * KFP + c] = (c < 784) ? (__bf16)w[r * 784 + c] : (__bf16)0.f;
}
__global__ __launch_bounds__(256) void cvt_w2(const float* __restrict__ w,
                                              __bf16* __restrict__ o) {
  const int i = blockIdx.x * 256 + threadIdx.x;
  o[i] = (__bf16)w[i];
}

// ======================= BatchNorm (training stats) ========================
__global__ __launch_bounds__(256) void bn_partial(const float* __restrict__ h,
                                                  float* __restrict__ partial) {
  const int blk = blockIdx.x;
  const int t = threadIdx.x;
  const float* p = h + (size_t)blk * 64 * NH + t;
  float s = 0.f, ss = 0.f;
#pragma unroll 4
  for (int r = 0; r < 64; r++) {
    const float v = p[(size_t)r * NH];
    s += v; ss += v * v;
  }
  partial[blk * 512 + t] = s;
  partial[blk * 512 + 256 + t] = ss;
}

__global__ __launch_bounds__(256) void bn_finalize(
    const float* __restrict__ partial, const float* __restrict__ g,
    const float* __restrict__ be, float* __restrict__ ab, float* __restrict__ cb) {
  const int t = threadIdx.x;
  float s = 0.f, ss = 0.f;
  for (int i = 0; i < 256; i++) {
    s += partial[i * 512 + t];
    ss += partial[i * 512 + 256 + t];
  }
  const float mean = s * (1.f / 16384.f);
  const float var = ss * (1.f / 16384.f) - mean * mean;
  const float rstd = rsqrtf(var + 1e-5f);
  const float a = g[t] * rstd;
  ab[t] = a;
  cb[t] = be[t] - mean * a;
}

__global__ __launch_bounds__(256) void bn_relu(float* __restrict__ h,
                                               __bf16* __restrict__ hb,
                                               const float* __restrict__ ab,
                                               const float* __restrict__ cb) {
  const size_t i = (size_t)blockIdx.x * 256 + threadIdx.x;
  float4 v = ((float4*)h)[i];
  const int col = (int)((i * 4) & (NH - 1));
  const float4 a = *(const float4*)(ab + col);
  const float4 c = *(const float4*)(cb + col);
  v.x = fmaxf(v.x * a.x + c.x, 0.f);
  v.y = fmaxf(v.y * a.y + c.y, 0.f);
  v.z = fmaxf(v.z * a.z + c.z, 0.f);
  v.w = fmaxf(v.w * a.w + c.w, 0.f);
  ((float4*)h)[i] = v;
  bf16x4 o = {(__bf16)v.x, (__bf16)v.y, (__bf16)v.z, (__bf16)v.w};
  *(bf16x4*)(hb + i * 4) = o;
}

__global__ __launch_bounds__(256) void bn_relu_res(float* __restrict__ h2,
                                                   const float* __restrict__ h1,
                                                   const float* __restrict__ ab,
                                                   const float* __restrict__ cb) {
  const size_t i = (size_t)blockIdx.x * 256 + threadIdx.x;
  float4 v = ((float4*)h2)[i];
  const float4 rsd = ((const float4*)h1)[i];
  const int col = (int)((i * 4) & (NH - 1));
  const float4 a = *(const float4*)(ab + col);
  const float4 c = *(const float4*)(cb + col);
  v.x = fmaxf(v.x * a.x + c.x, 0.f) + rsd.x;
  v.y = fmaxf(v.y * a.y + c.y, 0.f) + rsd.y;
  v.z = fmaxf(v.z * a.z + c.z, 0.f) + rsd.z;
  v.w = fmaxf(v.w * a.w + c.w, 0.f) + rsd.w;
  ((float4*)h2)[i] = v;
}

// ================ head: logits = h2 @ w3^T + b3, then log_softmax ==========
__global__ __launch_bounds__(256) void head_kernel(
    const float* __restrict__ h2, const float* __restrict__ w3,
    const float* __restrict__ b3, float* __restrict__ out) {
  __shared__ float w3s[NCLS * NH];
  for (int i = threadIdx.x; i < NCLS * NH; i += 256) w3s[i] = w3[i];
  __syncthreads();

  const int m = blockIdx.x * 256 + threadIdx.x;
  const float* hr = h2 + (size_t)m * NH;
  float acc[NCLS];
#pragma unroll
  for (int n = 0; n < NCLS; n++) acc[n] = b3[n];

  for (int k = 0; k < NH; k += 4) {
    const float4 hv = *(const float4*)(hr + k);
#pragma unroll
    for (int n = 0; n < NCLS; n++) {
      const float4 wv = *(const float4*)&w3s[n * NH + k];
      acc[n] += hv.x * wv.x + hv.y * wv.y + hv.z * wv.z + hv.w * wv.w;
    }
  }

  float mx = acc[0];
#pragma unroll
  for (int n = 1; n < NCLS; n++) mx = fmaxf(mx, acc[n]);
  float se = 0.f;
#pragma unroll
  for (int n = 0; n < NCLS; n++) se += expf(acc[n] - mx);
  const float lse = logf(se) + mx;
#pragma unroll
  for (int n = 0; n < NCLS; n++) out[(size_t)m * NCLS + n] = acc[n] - lse;
}

// =========================== launch ========================================
extern "C" void kernel_launch(void* const* d_in, const int* in_sizes, int n_in,
                              void* d_out, int out_size, void* d_ws, size_t ws_size,
                              hipStream_t stream) {
  const float* x   = (const float*)d_in[0];
  const float* qp  = (const float*)d_in[1];
  const float* w1  = (const float*)d_in[2];
  const float* b1  = (const float*)d_in[3];
  const float* g1  = (const float*)d_in[4];
  const float* be1 = (const float*)d_in[5];
  const float* w2  = (const float*)d_in[6];
  const float* b2  = (const float*)d_in[7];
  const float* g2  = (const float*)d_in[8];
  const float* be2 = (const float*)d_in[9];
  const float* w3  = (const float*)d_in[10];
  const float* b3  = (const float*)d_in[11];
  float* out = (float*)d_out;

  char* w = (char*)d_ws;
  __bf16* feats = (__bf16*)w;                         // 26,214,400
  float*  h1    = (float*)(w + 26214400);             // 16,777,216
  float*  h2    = (float*)(w + 42991616);             // 16,777,216
  __bf16* h1b   = (__bf16*)(w + 59768832);            //  8,388,608
  __bf16* w1b   = (__bf16*)(w + 68157440);            //    409,600
  __bf16* w2b   = (__bf16*)(w + 68567040);            //    131,072
  float*  partial = (float*)(w + 68698112);           //    524,288
  float*  ab1   = (float*)(w + 69222400);
  float*  cb1   = (float*)(w + 69223424);
  float*  ab2   = (float*)(w + 69224448);
  float*  cb2   = (float*)(w + 69225472);
  __bf16* Abuf  = (__bf16*)(w + 69226496);            //      4,096

  build_U<<<1, 256, 0, stream>>>(qp, Abuf);
  cvt_pad_w1<<<256, 256, 0, stream>>>(w1, w1b);
  cvt_w2<<<256, 256, 0, stream>>>(w2, w2b);

  quanv_mfma<<<BQ / 64, 256, 0, stream>>>(x, Abuf, feats);

  gemm_bf16_nt<<<dim3(BQ / GBM, NH / GBN), 256, 0, stream>>>(
      feats, w1b, b1, h1, BQ, NH, KFP);
  bn_partial<<<256, 256, 0, stream>>>(h1, partial);
  bn_finalize<<<1, 256, 0, stream>>>(partial, g1, be1, ab1, cb1);
  bn_relu<<<(BQ * NH / 4) / 256, 256, 0, stream>>>(h1, h1b, ab1, cb1);

  gemm_bf16_nt<<<dim3(BQ / GBM, NH / GBN), 256, 0, stream>>>(
      h1b, w2b, b2, h2, BQ, NH, NH);
  bn_partial<<<256, 256, 0, stream>>>(h2, partial);
  bn_finalize<<<1, 256, 0, stream>>>(partial, g2, be2, ab2, cb2);
  bn_relu_res<<<(BQ * NH / 4) / 256, 256, 0, stream>>>(h2, h1, ab2, cb2);

  head_kernel<<<BQ / 256, 256, 0, stream>>>(h2, w3, b3, out);
}

// Round 7
// 200.961 us; speedup vs baseline: 3.2619x; 1.1384x over previous
//
#include <hip/hip_runtime.h>
#include <math.h>

#define BQ 16384      // batch
#define KFP 800       // padded quanv feature dim (196*4 = 784, +16 zero pad)
#define NH 256        // hidden dim
#define NCLS 10

typedef float f32x4 __attribute__((ext_vector_type(4)));
typedef unsigned int u32x2 __attribute__((ext_vector_type(2)));
typedef unsigned int u32x4 __attribute__((ext_vector_type(4)));
typedef __bf16 bf16x8 __attribute__((ext_vector_type(8)));
typedef __bf16 bf16x4 __attribute__((ext_vector_type(4)));

// ===================== prep: build U + weight cvt + zero stats =============
// Amp index bits: wire w <-> bit (8>>w), matching reference flatten order.
// Component index k (B/K-dim): b4=w0? no: bit5=w0, bit4=ReIm (lane mapping).
// Abuf layout: flat f: m=f&7, row=(f>>3)&15, kg=(f>>7)&3, hl=(f>>9)&1, t=f>>10.

template<int ST>
__device__ __forceinline__ void u_ry(float* sr, float* si, float c, float s) {
#pragma unroll
  for (int i = 0; i < 16; i++) {
    if (i & ST) continue;
    const int j = i | ST;
    const float a0r = sr[i], a0i = si[i], a1r = sr[j], a1i = si[j];
    sr[i] = c * a0r - s * a1r;  si[i] = c * a0i - s * a1i;
    sr[j] = s * a0r + c * a1r;  si[j] = s * a0i + c * a1i;
  }
}
template<int ST>
__device__ __forceinline__ void u_rz(float* sr, float* si, float c, float s) {
#pragma unroll
  for (int i = 0; i < 16; i++) {
    const float pz = (i & ST) ? s : -s;
    const float ar = sr[i], ai = si[i];
    sr[i] = c * ar - pz * ai;
    si[i] = c * ai + pz * ar;
  }
}
template<int SC, int STG>
__device__ __forceinline__ void u_cnot(float* sr, float* si) {
#pragma unroll
  for (int i = 0; i < 16; i++) {
    if (!(i & SC) || (i & STG)) continue;
    const int j = i | STG;
    float t;
    t = sr[i]; sr[i] = sr[j]; sr[j] = t;
    t = si[i]; si[i] = si[j]; si[j] = t;
  }
}

__global__ __launch_bounds__(256) void prep_kernel(
    const float* __restrict__ qp, const float* __restrict__ w1,
    const float* __restrict__ w2, __bf16* __restrict__ Abuf,
    __bf16* __restrict__ w1b, __bf16* __restrict__ w2b,
    float* __restrict__ gs1, float* __restrict__ gs2) {
  const int bid = blockIdx.x;
  const int tid = threadIdx.x;
  if (bid == 0) {
    // zero BN stat accumulators (512 floats each)
    gs1[tid] = 0.f; gs1[256 + tid] = 0.f;
    gs2[tid] = 0.f; gs2[256 + tid] = 0.f;
    __shared__ float Ur[16][16], Ui[16][16];
    if (tid < 16) {
      float sr[16], si[16];
#pragma unroll
      for (int i = 0; i < 16; i++) { sr[i] = (i == tid) ? 1.f : 0.f; si[i] = 0.f; }
#pragma unroll
      for (int l = 0; l < 2; l++) {
        { const float t = qp[l*8 + 0] * 0.5f; u_ry<8>(sr, si, cosf(t), sinf(t)); }
        { const float t = qp[l*8 + 1] * 0.5f; u_rz<8>(sr, si, cosf(t), sinf(t)); }
        { const float t = qp[l*8 + 2] * 0.5f; u_ry<4>(sr, si, cosf(t), sinf(t)); }
        { const float t = qp[l*8 + 3] * 0.5f; u_rz<4>(sr, si, cosf(t), sinf(t)); }
        { const float t = qp[l*8 + 4] * 0.5f; u_ry<2>(sr, si, cosf(t), sinf(t)); }
        { const float t = qp[l*8 + 5] * 0.5f; u_rz<2>(sr, si, cosf(t), sinf(t)); }
        { const float t = qp[l*8 + 6] * 0.5f; u_ry<1>(sr, si, cosf(t), sinf(t)); }
        { const float t = qp[l*8 + 7] * 0.5f; u_rz<1>(sr, si, cosf(t), sinf(t)); }
        u_cnot<8, 4>(sr, si);
        u_cnot<4, 2>(sr, si);
        u_cnot<2, 1>(sr, si);
      }
#pragma unroll
      for (int r = 0; r < 16; r++) { Ur[r][tid] = sr[r]; Ui[r][tid] = si[r]; }
    }
    __syncthreads();
    for (int f = tid; f < 2048; f += 256) {
      const int m   = f & 7;
      const int row = (f >> 3) & 15;
      const int kg  = (f >> 7) & 3;
      const int hl  = (f >> 9) & 1;
      const int t   = (f >> 10) & 1;
      const int k   = kg * 8 + m;
      // lane mapping: bit5=w0, bit4=ReIm -> row bit3=w0, bit2=ReIm; k bit4=w0, bit3=ReIm
      const int ri_o  = (row >> 2) & 1;
      const int amp_o = ((row >> 3) & 1) * 8 + t * 4 + (row & 3);
      const int ri_i  = (k >> 3) & 1;
      const int amp_i = ((k >> 4) & 1) * 8 + (m >> 2) * 4 + (m & 3);
      const float u_r = Ur[amp_o][amp_i], u_i = Ui[amp_o][amp_i];
      float v = (ri_o == 0) ? ((ri_i == 0) ? u_r : -u_i)
                            : ((ri_i == 0) ? u_i : u_r);
      if (hl) {
        const __bf16 hb = (__bf16)v;
        v = v - (float)hb;
      }
      Abuf[f] = (__bf16)v;
    }
  } else if (bid <= 256) {
    const int r = bid - 1;
    for (int c = tid; c < KFP; c += 256)
      w1b[r * KFP + c] = (c < 784) ? (__bf16)w1[r * 784 + c] : (__bf16)0.f;
  } else {
    const int base = (bid - 257) * 2048 + tid * 8;
    const float4 v0 = *(const float4*)(w2 + base);
    const float4 v1 = *(const float4*)(w2 + base + 4);
    bf16x8 o = {(__bf16)v0.x, (__bf16)v0.y, (__bf16)v0.z, (__bf16)v0.w,
                (__bf16)v1.x, (__bf16)v1.y, (__bf16)v1.z, (__bf16)v1.w};
    *(bf16x8*)(w2b + base) = o;
  }
}

// ======================= quanv via MFMA ====================================
// 16 elements/wave: col = lane&15, kg = lane>>4; b5 = w0 amp-bit, b4 = ReIm.
// E: wires 1-3 register-local; wire0 = permlane32_swap (VALU, no LDS).
// Measurement deferred one iteration; trig pipelined one iteration ahead.

__device__ __forceinline__ float swz16(float v) {
  return __int_as_float(__builtin_amdgcn_ds_swizzle(__float_as_int(v), 0x401F));
}
__device__ __forceinline__ float pl32(float v, bool r0sel) {
  const u32x2 r = __builtin_amdgcn_permlane32_swap(
      __float_as_uint(v), __float_as_uint(v), false, false);
  return __uint_as_float(r0sel ? r.x : r.y);
}

__global__ __launch_bounds__(256) void quanv_mfma(
    const float* __restrict__ x, const __bf16* __restrict__ Abuf,
    __bf16* __restrict__ feats) {
  const int tid = threadIdx.x;
  const int l = tid & 63;
  const int wv = tid >> 6;
  const int col = l & 15;
  const int kg = l >> 4;
  const int b = blockIdx.x * 64 + wv * 16 + col;
  const float* xb = x + (size_t)b * 784;
  __bf16* fb = feats + (size_t)b * KFP;
  const float sg0 = (l & 32) ? 1.f : -1.f;   // wire0 amp-bit sign (b5)

  // permlane32 partner-selection mask (robust to operand-swap semantics)
  const u32x2 pt = __builtin_amdgcn_permlane32_swap((unsigned)l, (unsigned)l,
                                                    false, false);
  const bool p32r0 = (pt.x == (unsigned)(l ^ 32));

  // A fragments (held in VGPRs for the whole kernel)
  const bf16x8* Ab = (const bf16x8*)Abuf;
  const bf16x8 A0h = Ab[(0 * 4 + kg) * 16 + col];
  const bf16x8 A0l = Ab[(1 * 4 + kg) * 16 + col];
  const bf16x8 A1h = Ab[(2 * 4 + kg) * 16 + col];
  const bf16x8 A1l = Ab[(3 * 4 + kg) * 16 + col];

  f32x4 c0 = {(kg == 0) ? 1.f : 0.f, 0.f, 0.f, 0.f};
  f32x4 c1 = {0.f, 0.f, 0.f, 0.f};
  const f32x4 z4 = {0.f, 0.f, 0.f, 0.f};

  float cw[4], sw[4];   // trig for the CURRENT patch (pipelined)
  auto trig = [&](float2 a, float2 b2) {
    const float h0 = a.x * 0.5f, h1 = a.y * 0.5f;
    const float h2 = b2.x * 0.5f, h3 = b2.y * 0.5f;
    cw[0] = __cosf(h0); sw[0] = __sinf(h0);
    cw[1] = __cosf(h1); sw[1] = __sinf(h1);
    cw[2] = __cosf(h2); sw[2] = __sinf(h2);
    cw[3] = __cosf(h3); sw[3] = __sinf(h3);
  };

  // measurement of current state -> store 4 bf16 (lane kg==0)
  auto meas = [&](__bf16* dst) {
    const float sq0 = c0.x * c0.x, sq1 = c0.y * c0.y;
    const float sq2 = c0.z * c0.z, sq3 = c0.w * c0.w;
    const float sq4 = c1.x * c1.x, sq5 = c1.y * c1.y;
    const float sq6 = c1.z * c1.z, sq7 = c1.w * c1.w;
    const float s01 = sq0 + sq1, s23 = sq2 + sq3;
    const float s45 = sq4 + sq5, s67 = sq6 + sq7;
    const float d01 = sq0 - sq1, d23 = sq2 - sq3;
    const float d45 = sq4 - sq5, d67 = sq6 - sq7;
    const float z3 = (d01 + d23) + (d45 + d67);   // sign by w3
    const float z2 = (s01 - s23) + (s45 - s67);   // sign by w2
    const float q03 = s01 + s23, q47 = s45 + s67;
    const float z1 = q03 - q47;                   // sign by w1 (chain)
    const float T  = q03 + q47;
    const float z3a = z3 + swz16(z3);             // ReIm combine (bit4)
    const float z2a = z2 + swz16(z2);
    const float z1a = z1 + swz16(z1);
    const float Ta  = T + swz16(T);
    const float z3f = z3a + pl32(z3a, p32r0);     // w0 combine (bit5)
    const float z2f = z2a + pl32(z2a, p32r0);
    const float z1f = z1a + pl32(z1a, p32r0);
    const float z0f = sg0 * (pl32(Ta, p32r0) - Ta);
    if (kg == 0) {
      bf16x4 o = {(__bf16)z0f, (__bf16)z1f, (__bf16)z2f, (__bf16)z3f};
      *(bf16x4*)dst = o;
    }
  };

  // E(vals) + 6 independent MFMAs + tree add
  auto step = [&]() {
    float S[8] = {c0.x, c0.y, c0.z, c0.w, c1.x, c1.y, c1.z, c1.w};
    // wire1: pairs (i, i^4)
#pragma unroll
    for (int j = 0; j < 4; j++) {
      const float a = S[j];
      S[j]     = fmaf(-sw[1], S[4 + j], cw[1] * S[j]);
      S[4 + j] = fmaf( sw[1], a,        cw[1] * S[4 + j]);
    }
    // wire2: pairs (i, i^2)
#pragma unroll
    for (int base = 0; base < 8; base += 4)
#pragma unroll
      for (int j = 0; j < 2; j++) {
        const int i0 = base + j, i1 = base + j + 2;
        const float a = S[i0];
        S[i0] = fmaf(-sw[2], S[i1], cw[2] * S[i0]);
        S[i1] = fmaf( sw[2], a,     cw[2] * S[i1]);
      }
    // wire3: pairs (i, i^1)
#pragma unroll
    for (int i0 = 0; i0 < 8; i0 += 2) {
      const float a = S[i0];
      S[i0]     = fmaf(-sw[3], S[i0 + 1], cw[3] * S[i0]);
      S[i0 + 1] = fmaf( sw[3], a,         cw[3] * S[i0 + 1]);
    }
    // wire0: cross-lane bit5 via permlane32 (VALU)
    float P[8];
#pragma unroll
    for (int i = 0; i < 8; i++) P[i] = pl32(S[i], p32r0);
    const float ss0 = sg0 * sw[0];
#pragma unroll
    for (int i = 0; i < 8; i++) S[i] = fmaf(ss0, P[i], cw[0] * S[i]);

    // hi/lo split by truncation; pack via v_perm (hi16 of each fp32)
    unsigned sb[8], lb[8];
#pragma unroll
    for (int i = 0; i < 8; i++) {
      sb[i] = __float_as_uint(S[i]);
      lb[i] = __float_as_uint(S[i] - __uint_as_float(sb[i] & 0xFFFF0000u));
    }
    u32x4 bh, bl;
#pragma unroll
    for (int j = 0; j < 4; j++) {
      bh[j] = __builtin_amdgcn_perm(sb[2 * j + 1], sb[2 * j], 0x07060302u);
      bl[j] = __builtin_amdgcn_perm(lb[2 * j + 1], lb[2 * j], 0x07060302u);
    }
    const bf16x8 Bh = __builtin_bit_cast(bf16x8, bh);
    const bf16x8 Bl = __builtin_bit_cast(bf16x8, bl);

    // 6 independent MFMAs (depth 1) + tree add
    const f32x4 p0 = __builtin_amdgcn_mfma_f32_16x16x32_bf16(A0h, Bh, z4, 0, 0, 0);
    const f32x4 q0 = __builtin_amdgcn_mfma_f32_16x16x32_bf16(A0l, Bh, z4, 0, 0, 0);
    const f32x4 r0 = __builtin_amdgcn_mfma_f32_16x16x32_bf16(A0h, Bl, z4, 0, 0, 0);
    const f32x4 p1 = __builtin_amdgcn_mfma_f32_16x16x32_bf16(A1h, Bh, z4, 0, 0, 0);
    const f32x4 q1 = __builtin_amdgcn_mfma_f32_16x16x32_bf16(A1l, Bh, z4, 0, 0, 0);
    const f32x4 r1 = __builtin_amdgcn_mfma_f32_16x16x32_bf16(A1h, Bl, z4, 0, 0, 0);
    c0 = (p0 + q0) + r0;
    c1 = (p1 + q1) + r1;
  };

  // ---- software pipeline: trig one patch ahead, meas one patch behind ----
  {
    const float2 a0 = *(const float2*)(xb);
    const float2 a1 = *(const float2*)(xb + 28);
    trig(a0, a1);                       // trig for patch 0
  }
  float2 t0 = *(const float2*)(xb + 2); // values for patch 1
  float2 t1 = *(const float2*)(xb + 30);
  int nrr = 0, ncc = 2;                 // next-load counters (patch it+2)
  __bf16* fp = fb;

  for (int it = 0; it < 196; ++it) {
    const float* np = (it < 194) ? (xb + 56 * nrr + 2 * ncc) : xb;
    const float2 n0 = *(const float2*)np;
    const float2 n1 = *(const float2*)(np + 28);
    ncc++;
    if (ncc == 14) { ncc = 0; nrr++; }

    if (it > 0) { meas(fp); fp += 4; }  // measure s_{it-1}, overlaps step
    step();                             // uses cw/sw for patch it
    trig(t0, t1);                       // trig for patch it+1 (independent)
    t0 = n0; t1 = n1;
  }
  meas(fp);

  // zero the K padding 784..800
  if (kg == 0) {
    *(uint4*)(fb + 784) = (uint4){0, 0, 0, 0};
    *(uint4*)(fb + 792) = (uint4){0, 0, 0, 0};
  }
}

// ========== bf16 MFMA NT GEMM: C = A*B^T + bias, fused BN stats ============
// Also accumulates per-column sum / sumsq of C into gstats via atomics.
#define GBM 128
#define GBN 64
#define GBK 32

__device__ __forceinline__ void gld16(const void* g, void* l) {
  __builtin_amdgcn_global_load_lds(
      (const __attribute__((address_space(1))) unsigned int*)g,
      (__attribute__((address_space(3))) unsigned int*)l, 16, 0, 0);
}

__global__ __launch_bounds__(256) void gemm_bf16_nt(
    const __bf16* __restrict__ A, const __bf16* __restrict__ B,
    const float* __restrict__ bias, float* __restrict__ C,
    int M, int N, int K, float* __restrict__ gstats) {
  __shared__ char lds[24576];
  const int tid = threadIdx.x;
  const int bm = blockIdx.x * GBM;
  const int bn = blockIdx.y * GBN;
  const int NK = K / GBK;
  const size_t lda = (size_t)K * 2;

  const int srow = tid >> 2;
  const int lc16 = tid & 3;
  const int ag0 = lc16 ^ ((srow >> 1) & 3);
  const int ag1 = lc16 ^ (((srow + 64) >> 1) & 3);
  const char* a0p = (const char*)A + (size_t)(bm + srow) * lda + ag0 * 16;
  const char* a1p = (const char*)A + (size_t)(bm + 64 + srow) * lda + ag1 * 16;
  const char* b0p = (const char*)B + (size_t)(bn + srow) * lda + ag0 * 16;

  const int wid = tid >> 6, lane = tid & 63;
  const int wr = wid >> 1, wc = wid & 1;
  const int ln15 = lane & 15, ln4 = lane >> 4;
  int aoff[4], boff[2];
#pragma unroll
  for (int m = 0; m < 4; m++) {
    const int row = wr * 64 + m * 16 + ln15;
    aoff[m] = row * 64 + ((ln4 ^ ((row >> 1) & 3)) * 16);
  }
#pragma unroll
  for (int n = 0; n < 2; n++) {
    const int row = wc * 32 + n * 16 + ln15;
    boff[n] = 16384 + row * 64 + ((ln4 ^ ((row >> 1) & 3)) * 16);
  }

  f32x4 acc[4][2];
#pragma unroll
  for (int m = 0; m < 4; m++)
#pragma unroll
    for (int n = 0; n < 2; n++) acc[m][n] = (f32x4){0.f, 0.f, 0.f, 0.f};

  auto stage = [&](int buf, int kt) {
    const size_t kb = (size_t)kt * GBK * 2;
    char* as = lds + buf * 8192 + tid * 16;
    char* bs = lds + 16384 + buf * 4096 + tid * 16;
    gld16(a0p + kb, as);
    gld16(a1p + kb, as + 4096);
    gld16(b0p + kb, bs);
  };

  stage(0, 0);
  for (int kt = 0; kt < NK; kt++) {
    __syncthreads();
    if (kt + 1 < NK) stage((kt + 1) & 1, kt + 1);
    const int ab = (kt & 1) * 8192, bb = (kt & 1) * 4096;
    bf16x8 af[4], bfr[2];
#pragma unroll
    for (int m = 0; m < 4; m++) af[m] = *(const bf16x8*)(lds + ab + aoff[m]);
#pragma unroll
    for (int n = 0; n < 2; n++) bfr[n] = *(const bf16x8*)(lds + bb + boff[n]);
#pragma unroll
    for (int m = 0; m < 4; m++)
#pragma unroll
      for (int n = 0; n < 2; n++)
        acc[m][n] = __builtin_amdgcn_mfma_f32_16x16x32_bf16(af[m], bfr[n], acc[m][n], 0, 0, 0);
  }

  // epilogue: C write + per-block column stats (sum, sumsq)
  float csum[2], csq[2];
#pragma unroll
  for (int n = 0; n < 2; n++) {
    const int ccol = bn + wc * 32 + n * 16 + ln15;
    const float bv = bias[ccol];
    float s = 0.f, ss = 0.f;
#pragma unroll
    for (int m = 0; m < 4; m++) {
      const int crow = bm + wr * 64 + m * 16 + ln4 * 4;
#pragma unroll
      for (int r = 0; r < 4; r++) {
        const float v = acc[m][n][r] + bv;
        C[(size_t)(crow + r) * N + ccol] = v;
        s += v; ss += v * v;
      }
    }
    csum[n] = s; csq[n] = ss;
  }
  __syncthreads();                       // LDS staging reads done -> reuse
  float* sred = (float*)lds;             // [2 stats][4 wid][4 ln4][32 col]
#pragma unroll
  for (int n = 0; n < 2; n++) {
    const int slot = wid * 128 + ln4 * 32 + n * 16 + ln15;
    sred[slot] = csum[n];
    sred[512 + slot] = csq[n];
  }
  __syncthreads();
  if (tid < 128) {
    const int colb = tid & 63, which = tid >> 6;
    const int wcc = colb >> 5, c31 = colb & 31;
    float a = 0.f;
    const int base = which * 512 + c31;
#pragma unroll
    for (int w2_ = 0; w2_ < 2; w2_++)
#pragma unroll
      for (int l4 = 0; l4 < 4; l4++)
        a += sred[base + (w2_ * 2 + wcc) * 128 + l4 * 32];
    atomicAdd(&gstats[(bn + colb) * 2 + which], a);
  }
}

// ======================= BN finalize (from fused stats) ====================
__global__ __launch_bounds__(256) void bn_finalize_g(
    const float* __restrict__ gstats, const float* __restrict__ g,
    const float* __restrict__ be, float* __restrict__ ab, float* __restrict__ cb) {
  const int t = threadIdx.x;
  const float s = gstats[t * 2], ss = gstats[t * 2 + 1];
  const float mean = s * (1.f / 16384.f);
  const float var = ss * (1.f / 16384.f) - mean * mean;
  const float rstd = rsqrtf(var + 1e-5f);
  const float a = g[t] * rstd;
  ab[t] = a;
  cb[t] = be[t] - mean * a;
}

// BN+ReLU -> bf16 only (GEMM2 input + residual source)
__global__ __launch_bounds__(256) void bn_relu_cvt(
    const float* __restrict__ h, __bf16* __restrict__ hb,
    const float* __restrict__ ab, const float* __restrict__ cb) {
  const size_t i = (size_t)blockIdx.x * 256 + threadIdx.x;  // float4 index
  const float4 v = ((const float4*)h)[i];
  const int col = (int)((i * 4) & (NH - 1));
  const float4 a = *(const float4*)(ab + col);
  const float4 c = *(const float4*)(cb + col);
  bf16x4 o = {(__bf16)fmaxf(fmaf(v.x, a.x, c.x), 0.f),
              (__bf16)fmaxf(fmaf(v.y, a.y, c.y), 0.f),
              (__bf16)fmaxf(fmaf(v.z, a.z, c.z), 0.f),
              (__bf16)fmaxf(fmaf(v.w, a.w, c.w), 0.f)};
  *(bf16x4*)(hb + i * 4) = o;
}

// ========== fused tail: BN2 + ReLU + residual + head GEMV + log_softmax ====
__global__ __launch_bounds__(256) void tail_fused(
    const float* __restrict__ h2p, const __bf16* __restrict__ h1b,
    const float* __restrict__ ab, const float* __restrict__ cb,
    const float* __restrict__ w3, const float* __restrict__ b3,
    float* __restrict__ out) {
  __shared__ float w3s[NCLS * NH];
  __shared__ float as[NH], cs[NH];
  for (int i = threadIdx.x; i < NCLS * NH; i += 256) w3s[i] = w3[i];
  as[threadIdx.x] = ab[threadIdx.x];
  cs[threadIdx.x] = cb[threadIdx.x];
  __syncthreads();

  const int m = blockIdx.x * 256 + threadIdx.x;
  const float* hr = h2p + (size_t)m * NH;
  const __bf16* rr = h1b + (size_t)m * NH;
  float acc[NCLS];
#pragma unroll
  for (int n = 0; n < NCLS; n++) acc[n] = b3[n];

  for (int k = 0; k < NH; k += 8) {
    const float4 hv0 = *(const float4*)(hr + k);
    const float4 hv1 = *(const float4*)(hr + k + 4);
    const bf16x8 rv = *(const bf16x8*)(rr + k);
    float v[8] = {hv0.x, hv0.y, hv0.z, hv0.w, hv1.x, hv1.y, hv1.z, hv1.w};
#pragma unroll
    for (int j = 0; j < 8; j++)
      v[j] = fmaxf(fmaf(v[j], as[k + j], cs[k + j]), 0.f) + (float)rv[j];
#pragma unroll
    for (int n = 0; n < NCLS; n++) {
      float d = 0.f;
#pragma unroll
      for (int j = 0; j < 8; j++) d = fmaf(v[j], w3s[n * NH + k + j], d);
      acc[n] += d;
    }
  }

  float mx = acc[0];
#pragma unroll
  for (int n = 1; n < NCLS; n++) mx = fmaxf(mx, acc[n]);
  float se = 0.f;
#pragma unroll
  for (int n = 0; n < NCLS; n++) se += expf(acc[n] - mx);
  const float lse = logf(se) + mx;
#pragma unroll
  for (int n = 0; n < NCLS; n++) out[(size_t)m * NCLS + n] = acc[n] - lse;
}

// =========================== launch ========================================
extern "C" void kernel_launch(void* const* d_in, const int* in_sizes, int n_in,
                              void* d_out, int out_size, void* d_ws, size_t ws_size,
                              hipStream_t stream) {
  const float* x   = (const float*)d_in[0];
  const float* qp  = (const float*)d_in[1];
  const float* w1  = (const float*)d_in[2];
  const float* b1  = (const float*)d_in[3];
  const float* g1  = (const float*)d_in[4];
  const float* be1 = (const float*)d_in[5];
  const float* w2  = (const float*)d_in[6];
  const float* b2  = (const float*)d_in[7];
  const float* g2  = (const float*)d_in[8];
  const float* be2 = (const float*)d_in[9];
  const float* w3  = (const float*)d_in[10];
  const float* b3  = (const float*)d_in[11];
  float* out = (float*)d_out;

  char* w = (char*)d_ws;
  __bf16* feats = (__bf16*)w;                         // 26,214,400
  float*  h1    = (float*)(w + 26214400);             // 16,777,216
  float*  h2p   = (float*)(w + 42991616);             // 16,777,216
  __bf16* h1b   = (__bf16*)(w + 59768832);            //  8,388,608
  __bf16* w1b   = (__bf16*)(w + 68157440);            //    409,600
  __bf16* w2b   = (__bf16*)(w + 68567040);            //    131,072
  float*  gs1   = (float*)(w + 68698112);             //      2,048
  float*  gs2   = (float*)(w + 68700160);             //      2,048
  float*  ab1   = (float*)(w + 68702208);
  float*  cb1   = (float*)(w + 68703232);
  float*  ab2   = (float*)(w + 68704256);
  float*  cb2   = (float*)(w + 68705280);
  __bf16* Abuf  = (__bf16*)(w + 68706304);            //      4,096

  prep_kernel<<<289, 256, 0, stream>>>(qp, w1, w2, Abuf, w1b, w2b, gs1, gs2);
  quanv_mfma<<<BQ / 64, 256, 0, stream>>>(x, Abuf, feats);

  gemm_bf16_nt<<<dim3(BQ / GBM, NH / GBN), 256, 0, stream>>>(
      feats, w1b, b1, h1, BQ, NH, KFP, gs1);
  bn_finalize_g<<<1, 256, 0, stream>>>(gs1, g1, be1, ab1, cb1);
  bn_relu_cvt<<<(BQ * NH / 4) / 256, 256, 0, stream>>>(h1, h1b, ab1, cb1);

  gemm_bf16_nt<<<dim3(BQ / GBM, NH / GBN), 256, 0, stream>>>(
      h1b, w2b, b2, h2p, BQ, NH, NH, gs2);
  bn_finalize_g<<<1, 256, 0, stream>>>(gs2, g2, be2, ab2, cb2);

  tail_fused<<<BQ / 256, 256, 0, stream>>>(h2p, h1b, ab2, cb2, w3, b3, out);
}